// Round 1
// baseline (1512.894 us; speedup 1.0000x reference)
//
#include <hip/hip_runtime.h>

#define N_NODES 50000
#define N_EDGES 800000
// IN=64, HID=128, OUT=64

__global__ void deg_kernel(const int* __restrict__ src, const int* __restrict__ dst,
                           int* __restrict__ outdeg, int* __restrict__ indeg) {
    int e = blockIdx.x * blockDim.x + threadIdx.x;
    if (e < N_EDGES) {
        atomicAdd(&outdeg[src[e]], 1);
        atomicAdd(&indeg[dst[e]], 1);
    }
}

__global__ void norm_kernel(const int* __restrict__ outdeg, const int* __restrict__ indeg,
                            float* __restrict__ norm_src, float* __restrict__ norm_dst) {
    int i = blockIdx.x * blockDim.x + threadIdx.x;
    if (i < N_NODES) {
        norm_src[i] = 1.0f / sqrtf((float)max(outdeg[i], 1));
        norm_dst[i] = 1.0f / sqrtf((float)max(indeg[i], 1));
    }
}

// 16 threads per edge, each handles one float4 of the 64-wide feature row.
__global__ void scatter1_kernel(const float4* __restrict__ x4,
                                const int* __restrict__ src, const int* __restrict__ dst,
                                const float* __restrict__ norm_src,
                                float* __restrict__ agg) {
    int t = blockIdx.x * blockDim.x + threadIdx.x;
    int e = t >> 4;
    int f4 = t & 15;
    if (e >= N_EDGES) return;
    int s = src[e];
    int d = dst[e];
    float ns = norm_src[s];
    float4 v = x4[s * 16 + f4];
    float* o = agg + d * 64 + f4 * 4;
    atomicAdd(o + 0, v.x * ns);
    atomicAdd(o + 1, v.y * ns);
    atomicAdd(o + 2, v.z * ns);
    atomicAdd(o + 3, v.w * ns);
}

// [N,64] @ [64,128] + bias, relu, * norm_dst, then pre-scale by norm_src for layer 2.
__global__ __launch_bounds__(256) void gemm1_kernel(
        const float* __restrict__ agg, const float* __restrict__ W1,
        const float* __restrict__ b1, const float* __restrict__ norm_dst,
        const float* __restrict__ norm_src, float* __restrict__ h1s) {
    __shared__ float Ws[64 * 128];
    __shared__ float As[64][64];
    int tid = threadIdx.x;
    int rowbase = blockIdx.x * 64;
    for (int i = tid; i < 64 * 128; i += 256) Ws[i] = W1[i];
    for (int i = tid; i < 64 * 64; i += 256) {
        int r = rowbase + (i >> 6);
        As[i >> 6][i & 63] = (r < N_NODES) ? agg[r * 64 + (i & 63)] : 0.f;
    }
    __syncthreads();
    int c0 = tid & 31;
    int r0 = tid >> 5;  // 0..7
    float acc[8][4];
    #pragma unroll
    for (int j = 0; j < 8; j++)
        for (int l = 0; l < 4; l++) acc[j][l] = 0.f;
    for (int k = 0; k < 64; k++) {
        float w0 = Ws[k * 128 + c0];
        float w1 = Ws[k * 128 + c0 + 32];
        float w2 = Ws[k * 128 + c0 + 64];
        float w3 = Ws[k * 128 + c0 + 96];
        #pragma unroll
        for (int j = 0; j < 8; j++) {
            float a = As[r0 + j * 8][k];
            acc[j][0] += a * w0;
            acc[j][1] += a * w1;
            acc[j][2] += a * w2;
            acc[j][3] += a * w3;
        }
    }
    for (int j = 0; j < 8; j++) {
        int r = rowbase + r0 + j * 8;
        if (r >= N_NODES) continue;
        float nd = norm_dst[r];
        float ns = norm_src[r];
        #pragma unroll
        for (int l = 0; l < 4; l++) {
            int c = c0 + 32 * l;
            float v = acc[j][l] * nd + b1[c];
            v = fmaxf(v, 0.f);
            h1s[r * 128 + c] = v * ns;
        }
    }
}

// [N,128] @ [128,64]
__global__ __launch_bounds__(256) void gemm2_kernel(
        const float* __restrict__ h1s, const float* __restrict__ W2,
        float* __restrict__ h2) {
    __shared__ float Ws[128 * 64];
    __shared__ float As[64][128];
    int tid = threadIdx.x;
    int rowbase = blockIdx.x * 64;
    for (int i = tid; i < 128 * 64; i += 256) Ws[i] = W2[i];
    for (int i = tid; i < 64 * 128; i += 256) {
        int r = rowbase + (i >> 7);
        As[i >> 7][i & 127] = (r < N_NODES) ? h1s[r * 128 + (i & 127)] : 0.f;
    }
    __syncthreads();
    int c0 = tid & 31;
    int r0 = tid >> 5;
    float acc[8][2];
    #pragma unroll
    for (int j = 0; j < 8; j++) { acc[j][0] = 0.f; acc[j][1] = 0.f; }
    for (int k = 0; k < 128; k++) {
        float w0 = Ws[k * 64 + c0];
        float w1 = Ws[k * 64 + c0 + 32];
        #pragma unroll
        for (int j = 0; j < 8; j++) {
            float a = As[r0 + j * 8][k];
            acc[j][0] += a * w0;
            acc[j][1] += a * w1;
        }
    }
    for (int j = 0; j < 8; j++) {
        int r = rowbase + r0 + j * 8;
        if (r >= N_NODES) continue;
        h2[r * 64 + c0] = acc[j][0];
        h2[r * 64 + c0 + 32] = acc[j][1];
    }
}

__global__ void scatter2_kernel(const float4* __restrict__ h2_4,
                                const int* __restrict__ src, const int* __restrict__ dst,
                                float* __restrict__ out) {
    int t = blockIdx.x * blockDim.x + threadIdx.x;
    int e = t >> 4;
    int f4 = t & 15;
    if (e >= N_EDGES) return;
    int s = src[e];
    int d = dst[e];
    float4 v = h2_4[s * 16 + f4];
    float* o = out + d * 64 + f4 * 4;
    atomicAdd(o + 0, v.x);
    atomicAdd(o + 1, v.y);
    atomicAdd(o + 2, v.z);
    atomicAdd(o + 3, v.w);
}

__global__ void finalize_kernel(float4* __restrict__ out4, const float* __restrict__ norm_dst,
                                const float4* __restrict__ b2_4) {
    int t = blockIdx.x * blockDim.x + threadIdx.x;
    int r = t >> 4;
    int f4 = t & 15;
    if (r >= N_NODES) return;
    float nd = norm_dst[r];
    float4 v = out4[t];
    float4 b = b2_4[f4];
    v.x = v.x * nd + b.x;
    v.y = v.y * nd + b.y;
    v.z = v.z * nd + b.z;
    v.w = v.w * nd + b.w;
    out4[t] = v;
}

extern "C" void kernel_launch(void* const* d_in, const int* in_sizes, int n_in,
                              void* d_out, int out_size, void* d_ws, size_t ws_size,
                              hipStream_t stream) {
    const float* x  = (const float*)d_in[0];
    const float* W1 = (const float*)d_in[1];
    const float* b1 = (const float*)d_in[2];
    const float* W2 = (const float*)d_in[3];
    const float* b2 = (const float*)d_in[4];
    const int* src  = (const int*)d_in[5];
    const int* dst  = (const int*)d_in[6];
    float* out = (float*)d_out;

    int* outdeg = (int*)d_ws;
    int* indeg = outdeg + N_NODES;
    float* norm_src = (float*)(indeg + N_NODES);
    float* norm_dst = norm_src + N_NODES;
    float* agg1 = norm_dst + N_NODES;          // N*64
    float* h1s  = agg1 + (size_t)N_NODES * 64; // N*128
    float* h2   = agg1;                        // alias: agg1 dead after gemm1

    hipMemsetAsync(outdeg, 0, 2 * N_NODES * sizeof(int), stream);
    hipMemsetAsync(agg1, 0, (size_t)N_NODES * 64 * sizeof(float), stream);
    hipMemsetAsync(d_out, 0, (size_t)N_NODES * 64 * sizeof(float), stream);

    deg_kernel<<<(N_EDGES + 255) / 256, 256, 0, stream>>>(src, dst, outdeg, indeg);
    norm_kernel<<<(N_NODES + 255) / 256, 256, 0, stream>>>(outdeg, indeg, norm_src, norm_dst);
    scatter1_kernel<<<(N_EDGES * 16 + 255) / 256, 256, 0, stream>>>(
        (const float4*)x, src, dst, norm_src, agg1);
    gemm1_kernel<<<(N_NODES + 63) / 64, 256, 0, stream>>>(agg1, W1, b1, norm_dst, norm_src, h1s);
    gemm2_kernel<<<(N_NODES + 63) / 64, 256, 0, stream>>>(h1s, W2, h2);
    scatter2_kernel<<<(N_EDGES * 16 + 255) / 256, 256, 0, stream>>>(
        (const float4*)h2, src, dst, out);
    finalize_kernel<<<(N_NODES * 16 + 255) / 256, 256, 0, stream>>>(
        (float4*)out, norm_dst, (const float4*)b2);
}

// Round 2
// 408.860 us; speedup vs baseline: 3.7003x; 3.7003x over previous
//
#include <hip/hip_runtime.h>

#define N_NODES 50000
#define N_EDGES 800000
// IN=64, HID=128, OUT=64

__global__ void deg_kernel(const int* __restrict__ src, const int* __restrict__ dst,
                           int* __restrict__ outdeg, int* __restrict__ indeg) {
    int e = blockIdx.x * blockDim.x + threadIdx.x;
    if (e < N_EDGES) {
        atomicAdd(&outdeg[src[e]], 1);
        atomicAdd(&indeg[dst[e]], 1);
    }
}

__global__ void norm_kernel(const int* __restrict__ outdeg, const int* __restrict__ indeg,
                            float* __restrict__ norm_src, float* __restrict__ norm_dst) {
    int i = blockIdx.x * blockDim.x + threadIdx.x;
    if (i < N_NODES) {
        norm_src[i] = 1.0f / sqrtf((float)max(outdeg[i], 1));
        norm_dst[i] = 1.0f / sqrtf((float)max(indeg[i], 1));
    }
}

// Exclusive prefix scan of indeg -> row_start (N+1) and cursor copy. 1 block, 1024 thr.
__global__ __launch_bounds__(1024) void scan_kernel(const int* __restrict__ indeg,
                                                    int* __restrict__ row_start,
                                                    int* __restrict__ cursor) {
    __shared__ int partial[1024];
    int tid = threadIdx.x;
    const int CHUNK = (N_NODES + 1023) / 1024;
    int begin = tid * CHUNK;
    int end = min(begin + CHUNK, N_NODES);
    int sum = 0;
    for (int i = begin; i < end; i++) sum += indeg[i];
    partial[tid] = sum;
    __syncthreads();
    for (int off = 1; off < 1024; off <<= 1) {
        int v = (tid >= off) ? partial[tid - off] : 0;
        __syncthreads();
        partial[tid] += v;
        __syncthreads();
    }
    int base = (tid == 0) ? 0 : partial[tid - 1];
    for (int i = begin; i < end; i++) {
        row_start[i] = base;
        cursor[i] = base;
        base += indeg[i];
    }
    if (tid == 1023) row_start[N_NODES] = partial[1023];
}

// Bucket edges by dst: edge_src[csr position] = src node id.
__global__ void fill_csr_kernel(const int* __restrict__ src, const int* __restrict__ dst,
                                int* __restrict__ cursor, int* __restrict__ edge_src) {
    int e = blockIdx.x * blockDim.x + threadIdx.x;
    if (e < N_EDGES) {
        int pos = atomicAdd(&cursor[dst[e]], 1);
        edge_src[pos] = src[e];
    }
}

// One wave per dst node, lane = feature column (64). Pull-sum of norm_src-scaled x rows.
__global__ __launch_bounds__(256) void gather1_kernel(
        const float* __restrict__ x, const int* __restrict__ edge_src,
        const int* __restrict__ row_start, const float* __restrict__ norm_src,
        float* __restrict__ agg) {
    int node = (blockIdx.x * blockDim.x + threadIdx.x) >> 6;
    int lane = threadIdx.x & 63;
    if (node >= N_NODES) return;
    int beg = row_start[node];
    int end = row_start[node + 1];
    float acc = 0.f;
    for (int i = beg; i < end; i += 64) {
        int nrem = end - i;
        int ids = (lane < nrem) ? edge_src[i + lane] : 0;
        int cnt = min(nrem, 64);
        for (int j = 0; j < cnt; j++) {
            int s = __shfl(ids, j, 64);
            acc += x[s * 64 + lane] * norm_src[s];
        }
    }
    agg[node * 64 + lane] = acc;
}

// Pull-sum of h2 rows; fuse norm_dst scale + b2 bias (final output).
__global__ __launch_bounds__(256) void gather2_kernel(
        const float* __restrict__ h2, const int* __restrict__ edge_src,
        const int* __restrict__ row_start, const float* __restrict__ norm_dst,
        const float* __restrict__ b2, float* __restrict__ out) {
    int node = (blockIdx.x * blockDim.x + threadIdx.x) >> 6;
    int lane = threadIdx.x & 63;
    if (node >= N_NODES) return;
    int beg = row_start[node];
    int end = row_start[node + 1];
    float acc = 0.f;
    for (int i = beg; i < end; i += 64) {
        int nrem = end - i;
        int ids = (lane < nrem) ? edge_src[i + lane] : 0;
        int cnt = min(nrem, 64);
        for (int j = 0; j < cnt; j++) {
            int s = __shfl(ids, j, 64);
            acc += h2[s * 64 + lane];
        }
    }
    out[node * 64 + lane] = acc * norm_dst[node] + b2[lane];
}

// [N,64] @ [64,128] + bias, relu, * norm_dst, then pre-scale by norm_src for layer 2.
__global__ __launch_bounds__(256) void gemm1_kernel(
        const float* __restrict__ agg, const float* __restrict__ W1,
        const float* __restrict__ b1, const float* __restrict__ norm_dst,
        const float* __restrict__ norm_src, float* __restrict__ h1s) {
    __shared__ float Ws[64 * 128];
    __shared__ float As[64][64];
    int tid = threadIdx.x;
    int rowbase = blockIdx.x * 64;
    for (int i = tid; i < 64 * 128; i += 256) Ws[i] = W1[i];
    for (int i = tid; i < 64 * 64; i += 256) {
        int r = rowbase + (i >> 6);
        As[i >> 6][i & 63] = (r < N_NODES) ? agg[r * 64 + (i & 63)] : 0.f;
    }
    __syncthreads();
    int c0 = tid & 31;
    int r0 = tid >> 5;  // 0..7
    float acc[8][4];
    #pragma unroll
    for (int j = 0; j < 8; j++)
        for (int l = 0; l < 4; l++) acc[j][l] = 0.f;
    for (int k = 0; k < 64; k++) {
        float w0 = Ws[k * 128 + c0];
        float w1 = Ws[k * 128 + c0 + 32];
        float w2 = Ws[k * 128 + c0 + 64];
        float w3 = Ws[k * 128 + c0 + 96];
        #pragma unroll
        for (int j = 0; j < 8; j++) {
            float a = As[r0 + j * 8][k];
            acc[j][0] += a * w0;
            acc[j][1] += a * w1;
            acc[j][2] += a * w2;
            acc[j][3] += a * w3;
        }
    }
    for (int j = 0; j < 8; j++) {
        int r = rowbase + r0 + j * 8;
        if (r >= N_NODES) continue;
        float nd = norm_dst[r];
        float ns = norm_src[r];
        #pragma unroll
        for (int l = 0; l < 4; l++) {
            int c = c0 + 32 * l;
            float v = acc[j][l] * nd + b1[c];
            v = fmaxf(v, 0.f);
            h1s[r * 128 + c] = v * ns;
        }
    }
}

// [N,128] @ [128,64]
__global__ __launch_bounds__(256) void gemm2_kernel(
        const float* __restrict__ h1s, const float* __restrict__ W2,
        float* __restrict__ h2) {
    __shared__ float Ws[128 * 64];
    __shared__ float As[64][128];
    int tid = threadIdx.x;
    int rowbase = blockIdx.x * 64;
    for (int i = tid; i < 128 * 64; i += 256) Ws[i] = W2[i];
    for (int i = tid; i < 64 * 128; i += 256) {
        int r = rowbase + (i >> 7);
        As[i >> 7][i & 127] = (r < N_NODES) ? h1s[r * 128 + (i & 127)] : 0.f;
    }
    __syncthreads();
    int c0 = tid & 31;
    int r0 = tid >> 5;
    float acc[8][2];
    #pragma unroll
    for (int j = 0; j < 8; j++) { acc[j][0] = 0.f; acc[j][1] = 0.f; }
    for (int k = 0; k < 128; k++) {
        float w0 = Ws[k * 64 + c0];
        float w1 = Ws[k * 64 + c0 + 32];
        #pragma unroll
        for (int j = 0; j < 8; j++) {
            float a = As[r0 + j * 8][k];
            acc[j][0] += a * w0;
            acc[j][1] += a * w1;
        }
    }
    for (int j = 0; j < 8; j++) {
        int r = rowbase + r0 + j * 8;
        if (r >= N_NODES) continue;
        h2[r * 64 + c0] = acc[j][0];
        h2[r * 64 + c0 + 32] = acc[j][1];
    }
}

extern "C" void kernel_launch(void* const* d_in, const int* in_sizes, int n_in,
                              void* d_out, int out_size, void* d_ws, size_t ws_size,
                              hipStream_t stream) {
    const float* x  = (const float*)d_in[0];
    const float* W1 = (const float*)d_in[1];
    const float* b1 = (const float*)d_in[2];
    const float* W2 = (const float*)d_in[3];
    const float* b2 = (const float*)d_in[4];
    const int* src  = (const int*)d_in[5];
    const int* dst  = (const int*)d_in[6];
    float* out = (float*)d_out;

    int* outdeg = (int*)d_ws;                    // N
    int* indeg = outdeg + N_NODES;               // N
    float* norm_src = (float*)(indeg + N_NODES); // N
    float* norm_dst = norm_src + N_NODES;        // N
    int* row_start = (int*)(norm_dst + N_NODES); // N+1
    int* cursor = row_start + N_NODES + 1;       // N
    int* edge_src = cursor + N_NODES;            // E
    float* agg1 = (float*)(edge_src + N_EDGES);  // N*64
    float* h1s  = agg1 + (size_t)N_NODES * 64;   // N*128
    float* h2   = agg1;                          // alias: agg1 dead after gemm1

    hipMemsetAsync(outdeg, 0, 2 * N_NODES * sizeof(int), stream);

    deg_kernel<<<(N_EDGES + 255) / 256, 256, 0, stream>>>(src, dst, outdeg, indeg);
    norm_kernel<<<(N_NODES + 255) / 256, 256, 0, stream>>>(outdeg, indeg, norm_src, norm_dst);
    scan_kernel<<<1, 1024, 0, stream>>>(indeg, row_start, cursor);
    fill_csr_kernel<<<(N_EDGES + 255) / 256, 256, 0, stream>>>(src, dst, cursor, edge_src);
    gather1_kernel<<<(N_NODES * 64 + 255) / 256, 256, 0, stream>>>(
        x, edge_src, row_start, norm_src, agg1);
    gemm1_kernel<<<(N_NODES + 63) / 64, 256, 0, stream>>>(agg1, W1, b1, norm_dst, norm_src, h1s);
    gemm2_kernel<<<(N_NODES + 63) / 64, 256, 0, stream>>>(h1s, W2, h2);
    gather2_kernel<<<(N_NODES * 64 + 255) / 256, 256, 0, stream>>>(
        h2, edge_src, row_start, norm_dst, b2, out);
}

// Round 3
// 301.971 us; speedup vs baseline: 5.0101x; 1.3540x over previous
//
#include <hip/hip_runtime.h>

#define N_NODES 50000
#define N_EDGES 800000
#define SCAN_BLOCKS ((N_NODES + 255) / 256)   // 196
// IN=64, HID=128, OUT=64

__global__ void deg_kernel(const int* __restrict__ src, const int* __restrict__ dst,
                           int* __restrict__ outdeg, int* __restrict__ indeg) {
    int e = blockIdx.x * blockDim.x + threadIdx.x;
    if (e < N_EDGES) {
        atomicAdd(&outdeg[src[e]], 1);
        atomicAdd(&indeg[dst[e]], 1);
    }
}

// Stage 1: per-block inclusive scan of indeg -> tmp_incl; block totals -> bsum.
__global__ __launch_bounds__(256) void scan1_kernel(const int* __restrict__ indeg,
                                                    int* __restrict__ tmp_incl,
                                                    int* __restrict__ bsum) {
    __shared__ int lds[256];
    int tid = threadIdx.x;
    int i = blockIdx.x * 256 + tid;
    int v = (i < N_NODES) ? indeg[i] : 0;
    lds[tid] = v;
    __syncthreads();
    for (int off = 1; off < 256; off <<= 1) {
        int t = (tid >= off) ? lds[tid - off] : 0;
        __syncthreads();
        lds[tid] += t;
        __syncthreads();
    }
    if (i < N_NODES) tmp_incl[i] = lds[tid];
    if (tid == 255) bsum[blockIdx.x] = lds[255];
}

// Stage 2: exclusive scan of the 196 block sums (1 block). Also writes row_start[N].
__global__ __launch_bounds__(256) void scan2_kernel(const int* __restrict__ bsum,
                                                    int* __restrict__ bofs,
                                                    int* __restrict__ row_start) {
    __shared__ int lds[256];
    int tid = threadIdx.x;
    lds[tid] = (tid < SCAN_BLOCKS) ? bsum[tid] : 0;
    __syncthreads();
    for (int off = 1; off < 256; off <<= 1) {
        int t = (tid >= off) ? lds[tid - off] : 0;
        __syncthreads();
        lds[tid] += t;
        __syncthreads();
    }
    if (tid < SCAN_BLOCKS) bofs[tid] = (tid == 0) ? 0 : lds[tid - 1];
    if (tid == SCAN_BLOCKS - 1) row_start[N_NODES] = lds[tid];
}

// Stage 3: row_start/cursor finalize + fused norm computation.
__global__ __launch_bounds__(256) void scan3_kernel(const int* __restrict__ indeg,
                                                    const int* __restrict__ outdeg,
                                                    const int* __restrict__ tmp_incl,
                                                    const int* __restrict__ bofs,
                                                    int* __restrict__ row_start,
                                                    int* __restrict__ cursor,
                                                    float* __restrict__ norm_src,
                                                    float* __restrict__ norm_dst) {
    int i = blockIdx.x * 256 + threadIdx.x;
    if (i >= N_NODES) return;
    int id = indeg[i];
    int rs = bofs[blockIdx.x] + tmp_incl[i] - id;
    row_start[i] = rs;
    cursor[i] = rs;
    norm_src[i] = 1.0f / sqrtf((float)max(outdeg[i], 1));
    norm_dst[i] = 1.0f / sqrtf((float)max(id, 1));
}

// Bucket edges by dst: edge_src[csr position] = src node id.
__global__ void fill_csr_kernel(const int* __restrict__ src, const int* __restrict__ dst,
                                int* __restrict__ cursor, int* __restrict__ edge_src) {
    int e = blockIdx.x * blockDim.x + threadIdx.x;
    if (e < N_EDGES) {
        int pos = atomicAdd(&cursor[dst[e]], 1);
        edge_src[pos] = src[e];
    }
}

// One wave per dst node, lane = feature column (64). Pull-sum of norm_src-scaled x rows.
__global__ __launch_bounds__(256) void gather1_kernel(
        const float* __restrict__ x, const int* __restrict__ edge_src,
        const int* __restrict__ row_start, const float* __restrict__ norm_src,
        float* __restrict__ agg) {
    int node = (blockIdx.x * blockDim.x + threadIdx.x) >> 6;
    int lane = threadIdx.x & 63;
    if (node >= N_NODES) return;
    int beg = row_start[node];
    int end = row_start[node + 1];
    float acc = 0.f;
    for (int i = beg; i < end; i += 64) {
        int nrem = end - i;
        int ids = (lane < nrem) ? edge_src[i + lane] : 0;
        int cnt = min(nrem, 64);
        for (int j = 0; j < cnt; j++) {
            int s = __shfl(ids, j, 64);
            acc += x[s * 64 + lane] * norm_src[s];
        }
    }
    agg[node * 64 + lane] = acc;
}

// Pull-sum of h2 rows; fuse norm_dst scale + b2 bias (final output).
__global__ __launch_bounds__(256) void gather2_kernel(
        const float* __restrict__ h2, const int* __restrict__ edge_src,
        const int* __restrict__ row_start, const float* __restrict__ norm_dst,
        const float* __restrict__ b2, float* __restrict__ out) {
    int node = (blockIdx.x * blockDim.x + threadIdx.x) >> 6;
    int lane = threadIdx.x & 63;
    if (node >= N_NODES) return;
    int beg = row_start[node];
    int end = row_start[node + 1];
    float acc = 0.f;
    for (int i = beg; i < end; i += 64) {
        int nrem = end - i;
        int ids = (lane < nrem) ? edge_src[i + lane] : 0;
        int cnt = min(nrem, 64);
        for (int j = 0; j < cnt; j++) {
            int s = __shfl(ids, j, 64);
            acc += h2[s * 64 + lane];
        }
    }
    out[node * 64 + lane] = acc * norm_dst[node] + b2[lane];
}

// [N,64] @ [64,128] + bias, relu, * norm_dst, then pre-scale by norm_src for layer 2.
__global__ __launch_bounds__(256) void gemm1_kernel(
        const float* __restrict__ agg, const float* __restrict__ W1,
        const float* __restrict__ b1, const float* __restrict__ norm_dst,
        const float* __restrict__ norm_src, float* __restrict__ h1s) {
    __shared__ float Ws[64 * 128];
    __shared__ float As[64][64];
    int tid = threadIdx.x;
    int rowbase = blockIdx.x * 64;
    for (int i = tid; i < 64 * 128; i += 256) Ws[i] = W1[i];
    for (int i = tid; i < 64 * 64; i += 256) {
        int r = rowbase + (i >> 6);
        As[i >> 6][i & 63] = (r < N_NODES) ? agg[r * 64 + (i & 63)] : 0.f;
    }
    __syncthreads();
    int c0 = tid & 31;
    int r0 = tid >> 5;  // 0..7
    float acc[8][4];
    #pragma unroll
    for (int j = 0; j < 8; j++)
        for (int l = 0; l < 4; l++) acc[j][l] = 0.f;
    for (int k = 0; k < 64; k++) {
        float w0 = Ws[k * 128 + c0];
        float w1 = Ws[k * 128 + c0 + 32];
        float w2 = Ws[k * 128 + c0 + 64];
        float w3 = Ws[k * 128 + c0 + 96];
        #pragma unroll
        for (int j = 0; j < 8; j++) {
            float a = As[r0 + j * 8][k];
            acc[j][0] += a * w0;
            acc[j][1] += a * w1;
            acc[j][2] += a * w2;
            acc[j][3] += a * w3;
        }
    }
    for (int j = 0; j < 8; j++) {
        int r = rowbase + r0 + j * 8;
        if (r >= N_NODES) continue;
        float nd = norm_dst[r];
        float ns = norm_src[r];
        #pragma unroll
        for (int l = 0; l < 4; l++) {
            int c = c0 + 32 * l;
            float v = acc[j][l] * nd + b1[c];
            v = fmaxf(v, 0.f);
            h1s[r * 128 + c] = v * ns;
        }
    }
}

// [N,128] @ [128,64]
__global__ __launch_bounds__(256) void gemm2_kernel(
        const float* __restrict__ h1s, const float* __restrict__ W2,
        float* __restrict__ h2) {
    __shared__ float Ws[128 * 64];
    __shared__ float As[64][128];
    int tid = threadIdx.x;
    int rowbase = blockIdx.x * 64;
    for (int i = tid; i < 128 * 64; i += 256) Ws[i] = W2[i];
    for (int i = tid; i < 64 * 128; i += 256) {
        int r = rowbase + (i >> 7);
        As[i >> 7][i & 127] = (r < N_NODES) ? h1s[r * 128 + (i & 127)] : 0.f;
    }
    __syncthreads();
    int c0 = tid & 31;
    int r0 = tid >> 5;
    float acc[8][2];
    #pragma unroll
    for (int j = 0; j < 8; j++) { acc[j][0] = 0.f; acc[j][1] = 0.f; }
    for (int k = 0; k < 128; k++) {
        float w0 = Ws[k * 64 + c0];
        float w1 = Ws[k * 64 + c0 + 32];
        #pragma unroll
        for (int j = 0; j < 8; j++) {
            float a = As[r0 + j * 8][k];
            acc[j][0] += a * w0;
            acc[j][1] += a * w1;
        }
    }
    for (int j = 0; j < 8; j++) {
        int r = rowbase + r0 + j * 8;
        if (r >= N_NODES) continue;
        h2[r * 64 + c0] = acc[j][0];
        h2[r * 64 + c0 + 32] = acc[j][1];
    }
}

extern "C" void kernel_launch(void* const* d_in, const int* in_sizes, int n_in,
                              void* d_out, int out_size, void* d_ws, size_t ws_size,
                              hipStream_t stream) {
    const float* x  = (const float*)d_in[0];
    const float* W1 = (const float*)d_in[1];
    const float* b1 = (const float*)d_in[2];
    const float* W2 = (const float*)d_in[3];
    const float* b2 = (const float*)d_in[4];
    const int* src  = (const int*)d_in[5];
    const int* dst  = (const int*)d_in[6];
    float* out = (float*)d_out;

    int* outdeg = (int*)d_ws;                    // N
    int* indeg = outdeg + N_NODES;               // N
    float* norm_src = (float*)(indeg + N_NODES); // N
    float* norm_dst = norm_src + N_NODES;        // N
    int* row_start = (int*)(norm_dst + N_NODES); // N+1
    int* cursor = row_start + N_NODES + 1;       // N
    int* tmp_incl = cursor + N_NODES;            // N
    int* bsum = tmp_incl + N_NODES;              // SCAN_BLOCKS
    int* bofs = bsum + SCAN_BLOCKS;              // SCAN_BLOCKS
    int* edge_src = bofs + SCAN_BLOCKS;          // E
    float* agg1 = (float*)(edge_src + N_EDGES);  // N*64
    float* h1s  = agg1 + (size_t)N_NODES * 64;   // N*128
    float* h2   = agg1;                          // alias: agg1 dead after gemm1

    hipMemsetAsync(outdeg, 0, 2 * N_NODES * sizeof(int), stream);

    deg_kernel<<<(N_EDGES + 255) / 256, 256, 0, stream>>>(src, dst, outdeg, indeg);
    scan1_kernel<<<SCAN_BLOCKS, 256, 0, stream>>>(indeg, tmp_incl, bsum);
    scan2_kernel<<<1, 256, 0, stream>>>(bsum, bofs, row_start);
    scan3_kernel<<<SCAN_BLOCKS, 256, 0, stream>>>(indeg, outdeg, tmp_incl, bofs,
                                                  row_start, cursor, norm_src, norm_dst);
    fill_csr_kernel<<<(N_EDGES + 255) / 256, 256, 0, stream>>>(src, dst, cursor, edge_src);
    gather1_kernel<<<(N_NODES * 64 + 255) / 256, 256, 0, stream>>>(
        x, edge_src, row_start, norm_src, agg1);
    gemm1_kernel<<<(N_NODES + 63) / 64, 256, 0, stream>>>(agg1, W1, b1, norm_dst, norm_src, h1s);
    gemm2_kernel<<<(N_NODES + 63) / 64, 256, 0, stream>>>(h1s, W2, h2);
    gather2_kernel<<<(N_NODES * 64 + 255) / 256, 256, 0, stream>>>(
        h2, edge_src, row_start, norm_dst, b2, out);
}

// Round 4
// 228.121 us; speedup vs baseline: 6.6320x; 1.3237x over previous
//
#include <hip/hip_runtime.h>

#define N_NODES 50000
#define N_EDGES 800000
#define SCAN_BLOCKS ((N_NODES + 255) / 256)   // 196
#define CHUNKS 64
#define EDGES_PER_CHUNK (N_EDGES / CHUNKS)    // 12500
#define HALF_NODES 25000
#define WORDS_PER_HALF 12500                  // u32 words (2 packed u16 counts each)
#define REP_WORDS 25000                       // u32 words per (arr,chunk) replica
// IN=64, HID=128, OUT=64

// Per-chunk privatized histogram: block (arr, half, chunk) counts its 12500
// edges' ids falling in its node-half into packed-u16 LDS counters, then
// writes the 50KB replica non-atomically. No global atomics at all.
__global__ __launch_bounds__(256) void hist_kernel(const int* __restrict__ src,
                                                   const int* __restrict__ dst,
                                                   unsigned int* __restrict__ rep) {
    __shared__ unsigned int cnt[WORDS_PER_HALF];
    int bid = blockIdx.x;
    int chunk = bid & 63;
    int hf = (bid >> 6) & 1;
    int arr = bid >> 7;
    const int* ids = arr ? dst : src;
    int tid = threadIdx.x;
    for (int i = tid; i < WORDS_PER_HALF; i += 256) cnt[i] = 0;
    __syncthreads();
    int base = hf * HALF_NODES;
    int ebeg = chunk * EDGES_PER_CHUNK;
    for (int i = tid; i < EDGES_PER_CHUNK; i += 256) {
        int v = ids[ebeg + i] - base;
        if ((unsigned)v < (unsigned)HALF_NODES)
            atomicAdd(&cnt[v >> 1], 1u << ((v & 1) << 4));  // LDS atomic, packed u16
    }
    __syncthreads();
    unsigned int* o = rep + ((size_t)arr * CHUNKS + chunk) * REP_WORDS + hf * WORDS_PER_HALF;
    for (int i = tid; i < WORDS_PER_HALF; i += 256) o[i] = cnt[i];
}

// Stage 1: reduce dst replicas -> indeg; per-block inclusive scan -> tmp_incl, bsum.
__global__ __launch_bounds__(256) void scan1_kernel(const unsigned int* __restrict__ rep,
                                                    int* __restrict__ indeg,
                                                    int* __restrict__ tmp_incl,
                                                    int* __restrict__ bsum) {
    __shared__ int lds[256];
    int tid = threadIdx.x;
    int i = blockIdx.x * 256 + tid;
    int v = 0;
    if (i < N_NODES) {
        int w = i >> 1, sh = (i & 1) << 4;
        const unsigned int* repd = rep + (size_t)CHUNKS * REP_WORDS;  // arr=1 (dst)
        #pragma unroll 8
        for (int c = 0; c < CHUNKS; c++)
            v += (int)((repd[(size_t)c * REP_WORDS + w] >> sh) & 0xffffu);
        indeg[i] = v;
    }
    lds[tid] = v;
    __syncthreads();
    for (int off = 1; off < 256; off <<= 1) {
        int t = (tid >= off) ? lds[tid - off] : 0;
        __syncthreads();
        lds[tid] += t;
        __syncthreads();
    }
    if (i < N_NODES) tmp_incl[i] = lds[tid];
    if (tid == 255) bsum[blockIdx.x] = lds[255];
}

// Stage 2: exclusive scan of block sums (1 block). Also writes row_start[N].
__global__ __launch_bounds__(256) void scan2_kernel(const int* __restrict__ bsum,
                                                    int* __restrict__ bofs,
                                                    int* __restrict__ row_start) {
    __shared__ int lds[256];
    int tid = threadIdx.x;
    lds[tid] = (tid < SCAN_BLOCKS) ? bsum[tid] : 0;
    __syncthreads();
    for (int off = 1; off < 256; off <<= 1) {
        int t = (tid >= off) ? lds[tid - off] : 0;
        __syncthreads();
        lds[tid] += t;
        __syncthreads();
    }
    if (tid < SCAN_BLOCKS) bofs[tid] = (tid == 0) ? 0 : lds[tid - 1];
    if (tid == SCAN_BLOCKS - 1) row_start[N_NODES] = lds[tid];
}

// Stage 3: row_start/cursor finalize + reduce src replicas -> norms.
__global__ __launch_bounds__(256) void scan3_kernel(const unsigned int* __restrict__ rep,
                                                    const int* __restrict__ indeg,
                                                    const int* __restrict__ tmp_incl,
                                                    const int* __restrict__ bofs,
                                                    int* __restrict__ row_start,
                                                    int* __restrict__ cursor,
                                                    float* __restrict__ norm_src,
                                                    float* __restrict__ norm_dst) {
    int i = blockIdx.x * 256 + threadIdx.x;
    if (i >= N_NODES) return;
    int id = indeg[i];
    int rs = bofs[blockIdx.x] + tmp_incl[i] - id;
    row_start[i] = rs;
    cursor[i] = rs;
    int w = i >> 1, sh = (i & 1) << 4;
    int od = 0;
    #pragma unroll 8
    for (int c = 0; c < CHUNKS; c++)
        od += (int)((rep[(size_t)c * REP_WORDS + w] >> sh) & 0xffffu);  // arr=0 (src)
    norm_src[i] = 1.0f / sqrtf((float)max(od, 1));
    norm_dst[i] = 1.0f / sqrtf((float)max(id, 1));
}

// Bucket edges by dst: edge_src[csr position] = src node id.
__global__ void fill_csr_kernel(const int* __restrict__ src, const int* __restrict__ dst,
                                int* __restrict__ cursor, int* __restrict__ edge_src) {
    int e = blockIdx.x * blockDim.x + threadIdx.x;
    if (e < N_EDGES) {
        int pos = atomicAdd(&cursor[dst[e]], 1);
        edge_src[pos] = src[e];
    }
}

// One wave per dst node, lane = feature column. readlane -> SGPR src id ->
// saddr-form coalesced row load + scalar norm load.
__global__ __launch_bounds__(256) void gather1_kernel(
        const float* __restrict__ x, const int* __restrict__ edge_src,
        const int* __restrict__ row_start, const float* __restrict__ norm_src,
        float* __restrict__ agg) {
    int node = (blockIdx.x * blockDim.x + threadIdx.x) >> 6;
    int lane = threadIdx.x & 63;
    if (node >= N_NODES) return;
    int beg = row_start[node];
    int end = row_start[node + 1];
    float acc = 0.f;
    for (int i = beg; i < end; i += 64) {
        int cnt = min(end - i, 64);
        int ids = (lane < cnt) ? edge_src[i + lane] : 0;
        for (int j = 0; j < cnt; j++) {
            int s = __builtin_amdgcn_readlane(ids, j);
            acc += x[(size_t)s * 64 + lane] * norm_src[s];
        }
    }
    agg[(size_t)node * 64 + lane] = acc;
}

__global__ __launch_bounds__(256) void gather2_kernel(
        const float* __restrict__ h2, const int* __restrict__ edge_src,
        const int* __restrict__ row_start, const float* __restrict__ norm_dst,
        const float* __restrict__ b2, float* __restrict__ out) {
    int node = (blockIdx.x * blockDim.x + threadIdx.x) >> 6;
    int lane = threadIdx.x & 63;
    if (node >= N_NODES) return;
    int beg = row_start[node];
    int end = row_start[node + 1];
    float acc = 0.f;
    for (int i = beg; i < end; i += 64) {
        int cnt = min(end - i, 64);
        int ids = (lane < cnt) ? edge_src[i + lane] : 0;
        for (int j = 0; j < cnt; j++) {
            int s = __builtin_amdgcn_readlane(ids, j);
            acc += h2[(size_t)s * 64 + lane];
        }
    }
    out[(size_t)node * 64 + lane] = acc * norm_dst[node] + b2[lane];
}

// Fused: h1 = relu((agg@W1)*nd + b1)*ns kept in LDS; h2 = h1 @ W2.
// 64KB union LDS: phase A {W1[64][128], As[64][64]}, phase B {Hs[64][128], W2s[128][64]}.
__global__ __launch_bounds__(256) void gemm_fused_kernel(
        const float* __restrict__ agg, const float* __restrict__ W1,
        const float* __restrict__ b1, const float* __restrict__ W2,
        const float* __restrict__ norm_dst, const float* __restrict__ norm_src,
        float* __restrict__ h2) {
    __shared__ float mem[16384];
    float* Ws = mem;          // 8192
    float* As = mem + 8192;   // 4096
    int tid = threadIdx.x;
    int rowbase = blockIdx.x * 64;
    for (int i = tid; i < 8192; i += 256) Ws[i] = W1[i];
    for (int i = tid; i < 4096; i += 256) {
        int r = rowbase + (i >> 6);
        As[i] = (r < N_NODES) ? agg[(size_t)r * 64 + (i & 63)] : 0.f;
    }
    __syncthreads();
    int c0 = tid & 31;
    int r0 = tid >> 5;  // 0..7
    float acc[8][4];
    #pragma unroll
    for (int j = 0; j < 8; j++)
        for (int l = 0; l < 4; l++) acc[j][l] = 0.f;
    for (int k = 0; k < 64; k++) {
        float w0 = Ws[k * 128 + c0];
        float w1 = Ws[k * 128 + c0 + 32];
        float w2 = Ws[k * 128 + c0 + 64];
        float w3 = Ws[k * 128 + c0 + 96];
        #pragma unroll
        for (int j = 0; j < 8; j++) {
            float a = As[(r0 + j * 8) * 64 + k];
            acc[j][0] += a * w0;
            acc[j][1] += a * w1;
            acc[j][2] += a * w2;
            acc[j][3] += a * w3;
        }
    }
    __syncthreads();  // done with Ws/As
    float* Hs = mem;          // [64][128]
    float* W2s = mem + 8192;  // [128][64]
    for (int i = tid; i < 8192; i += 256) W2s[i] = W2[i];
    for (int j = 0; j < 8; j++) {
        int r = rowbase + r0 + j * 8;
        float nd = (r < N_NODES) ? norm_dst[r] : 0.f;
        float ns = (r < N_NODES) ? norm_src[r] : 0.f;
        #pragma unroll
        for (int l = 0; l < 4; l++) {
            int c = c0 + 32 * l;
            Hs[(r0 + j * 8) * 128 + c] = fmaxf(acc[j][l] * nd + b1[c], 0.f) * ns;
        }
    }
    __syncthreads();
    float acc2[8][2];
    #pragma unroll
    for (int j = 0; j < 8; j++) { acc2[j][0] = 0.f; acc2[j][1] = 0.f; }
    for (int k = 0; k < 128; k++) {
        float w0 = W2s[k * 64 + c0];
        float w1 = W2s[k * 64 + c0 + 32];
        #pragma unroll
        for (int j = 0; j < 8; j++) {
            float a = Hs[(r0 + j * 8) * 128 + k];
            acc2[j][0] += a * w0;
            acc2[j][1] += a * w1;
        }
    }
    for (int j = 0; j < 8; j++) {
        int r = rowbase + r0 + j * 8;
        if (r >= N_NODES) continue;
        h2[(size_t)r * 64 + c0] = acc2[j][0];
        h2[(size_t)r * 64 + c0 + 32] = acc2[j][1];
    }
}

extern "C" void kernel_launch(void* const* d_in, const int* in_sizes, int n_in,
                              void* d_out, int out_size, void* d_ws, size_t ws_size,
                              hipStream_t stream) {
    const float* x  = (const float*)d_in[0];
    const float* W1 = (const float*)d_in[1];
    const float* b1 = (const float*)d_in[2];
    const float* W2 = (const float*)d_in[3];
    const float* b2 = (const float*)d_in[4];
    const int* src  = (const int*)d_in[5];
    const int* dst  = (const int*)d_in[6];
    float* out = (float*)d_out;

    int* indeg = (int*)d_ws;                        // N
    float* norm_src = (float*)(indeg + N_NODES);    // N
    float* norm_dst = norm_src + N_NODES;           // N
    int* row_start = (int*)(norm_dst + N_NODES);    // N+1
    int* cursor = row_start + N_NODES + 1;          // N
    int* tmp_incl = cursor + N_NODES;               // N
    int* bsum = tmp_incl + N_NODES;                 // SCAN_BLOCKS
    int* bofs = bsum + SCAN_BLOCKS;                 // SCAN_BLOCKS
    unsigned int* rep = (unsigned int*)(bofs + SCAN_BLOCKS);  // 2*64*25000 u32
    int* edge_src = (int*)(rep + (size_t)2 * CHUNKS * REP_WORDS); // E
    float* agg1 = (float*)(edge_src + N_EDGES);     // N*64
    float* h2   = agg1 + (size_t)N_NODES * 64;      // N*64

    hist_kernel<<<256, 256, 0, stream>>>(src, dst, rep);
    scan1_kernel<<<SCAN_BLOCKS, 256, 0, stream>>>(rep, indeg, tmp_incl, bsum);
    scan2_kernel<<<1, 256, 0, stream>>>(bsum, bofs, row_start);
    scan3_kernel<<<SCAN_BLOCKS, 256, 0, stream>>>(rep, indeg, tmp_incl, bofs,
                                                  row_start, cursor, norm_src, norm_dst);
    fill_csr_kernel<<<(N_EDGES + 255) / 256, 256, 0, stream>>>(src, dst, cursor, edge_src);
    gather1_kernel<<<(N_NODES * 64) / 256, 256, 0, stream>>>(
        x, edge_src, row_start, norm_src, agg1);
    gemm_fused_kernel<<<(N_NODES + 63) / 64, 256, 0, stream>>>(
        agg1, W1, b1, W2, norm_dst, norm_src, h2);
    gather2_kernel<<<(N_NODES * 64) / 256, 256, 0, stream>>>(
        h2, edge_src, row_start, norm_dst, b2, out);
}

// Round 5
// 183.222 us; speedup vs baseline: 8.2571x; 1.2450x over previous
//
#include <hip/hip_runtime.h>

#define N_NODES 50000
#define N_EDGES 800000
#define SCAN_BLOCKS ((N_NODES + 255) / 256)   // 196
#define CHUNKS 64
#define EDGES_PER_CHUNK (N_EDGES / CHUNKS)    // 12500
#define HALF_NODES 25000
#define WORDS_PER_HALF 12500                  // u32 words (2 packed u16 counts each)
#define REP_WORDS 25000                       // u32 words per (arr,chunk) replica
// IN=64, HID=128, OUT=64

typedef unsigned short ushort_t;

static __device__ __forceinline__ ushort_t f2bf(float f) {
    unsigned u = __float_as_uint(f);
    unsigned r = (u + 0x7fffu + ((u >> 16) & 1u)) >> 16;   // RNE
    return (ushort_t)r;
}
static __device__ __forceinline__ float bf2f(ushort_t u) {
    return __uint_as_float(((unsigned)u) << 16);
}

// Per-chunk privatized histogram: block (arr, half, chunk) counts its 12500
// edges' ids falling in its node-half into packed-u16 LDS counters, then
// writes the 50KB replica non-atomically. No global atomics.
__global__ __launch_bounds__(256) void hist_kernel(const int* __restrict__ src,
                                                   const int* __restrict__ dst,
                                                   unsigned int* __restrict__ rep) {
    __shared__ unsigned int cnt[WORDS_PER_HALF];
    int bid = blockIdx.x;
    int chunk = bid & 63;
    int hf = (bid >> 6) & 1;
    int arr = bid >> 7;
    const int* ids = arr ? dst : src;
    int tid = threadIdx.x;
    for (int i = tid; i < WORDS_PER_HALF; i += 256) cnt[i] = 0;
    __syncthreads();
    int base = hf * HALF_NODES;
    int ebeg = chunk * EDGES_PER_CHUNK;
    for (int i = tid; i < EDGES_PER_CHUNK; i += 256) {
        int v = ids[ebeg + i] - base;
        if ((unsigned)v < (unsigned)HALF_NODES)
            atomicAdd(&cnt[v >> 1], 1u << ((v & 1) << 4));  // LDS atomic, packed u16
    }
    __syncthreads();
    unsigned int* o = rep + ((size_t)arr * CHUNKS + chunk) * REP_WORDS + hf * WORDS_PER_HALF;
    for (int i = tid; i < WORDS_PER_HALF; i += 256) o[i] = cnt[i];
}

// Stage 1: reduce dst replicas -> indeg; per-block inclusive scan -> tmp_incl, bsum.
__global__ __launch_bounds__(256) void scan1_kernel(const unsigned int* __restrict__ rep,
                                                    int* __restrict__ indeg,
                                                    int* __restrict__ tmp_incl,
                                                    int* __restrict__ bsum) {
    __shared__ int lds[256];
    int tid = threadIdx.x;
    int i = blockIdx.x * 256 + tid;
    int v = 0;
    if (i < N_NODES) {
        int w = i >> 1, sh = (i & 1) << 4;
        const unsigned int* repd = rep + (size_t)CHUNKS * REP_WORDS;  // arr=1 (dst)
        #pragma unroll 8
        for (int c = 0; c < CHUNKS; c++)
            v += (int)((repd[(size_t)c * REP_WORDS + w] >> sh) & 0xffffu);
        indeg[i] = v;
    }
    lds[tid] = v;
    __syncthreads();
    for (int off = 1; off < 256; off <<= 1) {
        int t = (tid >= off) ? lds[tid - off] : 0;
        __syncthreads();
        lds[tid] += t;
        __syncthreads();
    }
    if (i < N_NODES) tmp_incl[i] = lds[tid];
    if (tid == 255) bsum[blockIdx.x] = lds[255];
}

// Stage 2: exclusive scan of block sums (1 block). Also writes row_start[N].
__global__ __launch_bounds__(256) void scan2_kernel(const int* __restrict__ bsum,
                                                    int* __restrict__ bofs,
                                                    int* __restrict__ row_start) {
    __shared__ int lds[256];
    int tid = threadIdx.x;
    lds[tid] = (tid < SCAN_BLOCKS) ? bsum[tid] : 0;
    __syncthreads();
    for (int off = 1; off < 256; off <<= 1) {
        int t = (tid >= off) ? lds[tid - off] : 0;
        __syncthreads();
        lds[tid] += t;
        __syncthreads();
    }
    if (tid < SCAN_BLOCKS) bofs[tid] = (tid == 0) ? 0 : lds[tid - 1];
    if (tid == SCAN_BLOCKS - 1) row_start[N_NODES] = lds[tid];
}

// Stage 3: row_start finalize + reduce src replicas -> norms.
__global__ __launch_bounds__(256) void scan3_kernel(const unsigned int* __restrict__ rep,
                                                    const int* __restrict__ indeg,
                                                    const int* __restrict__ tmp_incl,
                                                    const int* __restrict__ bofs,
                                                    int* __restrict__ row_start,
                                                    float* __restrict__ norm_src,
                                                    float* __restrict__ norm_dst) {
    int i = blockIdx.x * 256 + threadIdx.x;
    if (i >= N_NODES) return;
    int id = indeg[i];
    row_start[i] = bofs[blockIdx.x] + tmp_incl[i] - id;
    int w = i >> 1, sh = (i & 1) << 4;
    int od = 0;
    #pragma unroll 8
    for (int c = 0; c < CHUNKS; c++)
        od += (int)((rep[(size_t)c * REP_WORDS + w] >> sh) & 0xffffu);  // arr=0 (src)
    norm_src[i] = 1.0f / sqrtf((float)max(od, 1));
    norm_dst[i] = 1.0f / sqrtf((float)max(id, 1));
}

// Per-node running offset across chunks: cbase[c][node] = row_start[node] +
// sum_{c'<c} dst_count[c'][node].
__global__ __launch_bounds__(256) void chunk_scan_kernel(
        const unsigned int* __restrict__ rep, const int* __restrict__ row_start,
        int* __restrict__ cbase) {
    int i = blockIdx.x * 256 + threadIdx.x;
    if (i >= N_NODES) return;
    int w = i >> 1, sh = (i & 1) << 4;
    const unsigned int* repd = rep + (size_t)CHUNKS * REP_WORDS;  // arr=1 (dst)
    int running = row_start[i];
    for (int c = 0; c < CHUNKS; c++) {
        cbase[(size_t)c * N_NODES + i] = running;
        running += (int)((repd[(size_t)c * REP_WORDS + w] >> sh) & 0xffffu);
    }
}

// Counting-sort CSR fill: block (half, chunk) ranks its edges with packed-u16
// LDS cursors; pos = cbase[chunk][dst] + rank. No global atomics.
__global__ __launch_bounds__(256) void fill2_kernel(const int* __restrict__ src,
                                                    const int* __restrict__ dst,
                                                    const int* __restrict__ cbase,
                                                    int* __restrict__ edge_src) {
    __shared__ unsigned int rank[WORDS_PER_HALF];
    int chunk = blockIdx.x & 63;
    int hf = blockIdx.x >> 6;
    int tid = threadIdx.x;
    for (int i = tid; i < WORDS_PER_HALF; i += 256) rank[i] = 0;
    __syncthreads();
    int base = hf * HALF_NODES;
    int ebeg = chunk * EDGES_PER_CHUNK;
    for (int i = tid; i < EDGES_PER_CHUNK; i += 256) {
        int d = dst[ebeg + i];
        int v = d - base;
        if ((unsigned)v < (unsigned)HALF_NODES) {
            int sh = (v & 1) << 4;
            unsigned old = atomicAdd(&rank[v >> 1], 1u << sh);
            int r = (int)((old >> sh) & 0xffffu);
            edge_src[cbase[(size_t)chunk * N_NODES + d] + r] = src[ebeg + i];
        }
    }
}

// xs = bf16(x * norm_src), row-broadcast scale.
__global__ __launch_bounds__(256) void prescale_kernel(const float* __restrict__ x,
                                                       const float* __restrict__ norm_src,
                                                       ushort_t* __restrict__ xs) {
    int t = blockIdx.x * 256 + threadIdx.x;   // over N*64, exact grid
    int row = t >> 6;
    float ns = norm_src[row];
    xs[t] = f2bf(x[t] * ns);
}

// One wave per dst node, lane = feature column. 4-deep unroll for MLP.
__global__ __launch_bounds__(256) void gather1_kernel(
        const ushort_t* __restrict__ xs, const int* __restrict__ edge_src,
        const int* __restrict__ row_start, float* __restrict__ agg) {
    int node = (blockIdx.x * blockDim.x + threadIdx.x) >> 6;
    int lane = threadIdx.x & 63;
    int beg = row_start[node];
    int end = row_start[node + 1];
    float a0 = 0.f, a1 = 0.f, a2 = 0.f, a3 = 0.f;
    for (int i = beg; i < end; i += 64) {
        int cnt = min(end - i, 64);
        int ids = (lane < cnt) ? edge_src[i + lane] : 0;
        int j = 0;
        for (; j + 4 <= cnt; j += 4) {
            int s0 = __builtin_amdgcn_readlane(ids, j);
            int s1 = __builtin_amdgcn_readlane(ids, j + 1);
            int s2 = __builtin_amdgcn_readlane(ids, j + 2);
            int s3 = __builtin_amdgcn_readlane(ids, j + 3);
            float v0 = bf2f(xs[(size_t)s0 * 64 + lane]);
            float v1 = bf2f(xs[(size_t)s1 * 64 + lane]);
            float v2 = bf2f(xs[(size_t)s2 * 64 + lane]);
            float v3 = bf2f(xs[(size_t)s3 * 64 + lane]);
            a0 += v0; a1 += v1; a2 += v2; a3 += v3;
        }
        for (; j < cnt; j++) {
            int s = __builtin_amdgcn_readlane(ids, j);
            a0 += bf2f(xs[(size_t)s * 64 + lane]);
        }
    }
    agg[(size_t)node * 64 + lane] = (a0 + a1) + (a2 + a3);
}

__global__ __launch_bounds__(256) void gather2_kernel(
        const ushort_t* __restrict__ h2, const int* __restrict__ edge_src,
        const int* __restrict__ row_start, const float* __restrict__ norm_dst,
        const float* __restrict__ b2, float* __restrict__ out) {
    int node = (blockIdx.x * blockDim.x + threadIdx.x) >> 6;
    int lane = threadIdx.x & 63;
    int beg = row_start[node];
    int end = row_start[node + 1];
    float a0 = 0.f, a1 = 0.f, a2 = 0.f, a3 = 0.f;
    for (int i = beg; i < end; i += 64) {
        int cnt = min(end - i, 64);
        int ids = (lane < cnt) ? edge_src[i + lane] : 0;
        int j = 0;
        for (; j + 4 <= cnt; j += 4) {
            int s0 = __builtin_amdgcn_readlane(ids, j);
            int s1 = __builtin_amdgcn_readlane(ids, j + 1);
            int s2 = __builtin_amdgcn_readlane(ids, j + 2);
            int s3 = __builtin_amdgcn_readlane(ids, j + 3);
            float v0 = bf2f(h2[(size_t)s0 * 64 + lane]);
            float v1 = bf2f(h2[(size_t)s1 * 64 + lane]);
            float v2 = bf2f(h2[(size_t)s2 * 64 + lane]);
            float v3 = bf2f(h2[(size_t)s3 * 64 + lane]);
            a0 += v0; a1 += v1; a2 += v2; a3 += v3;
        }
        for (; j < cnt; j++) {
            int s = __builtin_amdgcn_readlane(ids, j);
            a0 += bf2f(h2[(size_t)s * 64 + lane]);
        }
    }
    float acc = (a0 + a1) + (a2 + a3);
    out[(size_t)node * 64 + lane] = acc * norm_dst[node] + b2[lane];
}

// Fused: h1 = relu((agg@W1)*nd + b1)*ns in LDS; h2 = bf16(h1 @ W2).
__global__ __launch_bounds__(256) void gemm_fused_kernel(
        const float* __restrict__ agg, const float* __restrict__ W1,
        const float* __restrict__ b1, const float* __restrict__ W2,
        const float* __restrict__ norm_dst, const float* __restrict__ norm_src,
        ushort_t* __restrict__ h2) {
    __shared__ float mem[16384];
    float* Ws = mem;          // 8192
    float* As = mem + 8192;   // 4096
    int tid = threadIdx.x;
    int rowbase = blockIdx.x * 64;
    for (int i = tid; i < 8192; i += 256) Ws[i] = W1[i];
    for (int i = tid; i < 4096; i += 256) {
        int r = rowbase + (i >> 6);
        As[i] = (r < N_NODES) ? agg[(size_t)r * 64 + (i & 63)] : 0.f;
    }
    __syncthreads();
    int c0 = tid & 31;
    int r0 = tid >> 5;  // 0..7
    float acc[8][4];
    #pragma unroll
    for (int j = 0; j < 8; j++)
        for (int l = 0; l < 4; l++) acc[j][l] = 0.f;
    for (int k = 0; k < 64; k++) {
        float w0 = Ws[k * 128 + c0];
        float w1 = Ws[k * 128 + c0 + 32];
        float w2 = Ws[k * 128 + c0 + 64];
        float w3 = Ws[k * 128 + c0 + 96];
        #pragma unroll
        for (int j = 0; j < 8; j++) {
            float a = As[(r0 + j * 8) * 64 + k];
            acc[j][0] += a * w0;
            acc[j][1] += a * w1;
            acc[j][2] += a * w2;
            acc[j][3] += a * w3;
        }
    }
    __syncthreads();  // done with Ws/As
    float* Hs = mem;          // [64][128]
    float* W2s = mem + 8192;  // [128][64]
    for (int i = tid; i < 8192; i += 256) W2s[i] = W2[i];
    for (int j = 0; j < 8; j++) {
        int r = rowbase + r0 + j * 8;
        float nd = (r < N_NODES) ? norm_dst[r] : 0.f;
        float ns = (r < N_NODES) ? norm_src[r] : 0.f;
        #pragma unroll
        for (int l = 0; l < 4; l++) {
            int c = c0 + 32 * l;
            Hs[(r0 + j * 8) * 128 + c] = fmaxf(acc[j][l] * nd + b1[c], 0.f) * ns;
        }
    }
    __syncthreads();
    float acc2[8][2];
    #pragma unroll
    for (int j = 0; j < 8; j++) { acc2[j][0] = 0.f; acc2[j][1] = 0.f; }
    for (int k = 0; k < 128; k++) {
        float w0 = W2s[k * 64 + c0];
        float w1 = W2s[k * 64 + c0 + 32];
        #pragma unroll
        for (int j = 0; j < 8; j++) {
            float a = Hs[(r0 + j * 8) * 128 + k];
            acc2[j][0] += a * w0;
            acc2[j][1] += a * w1;
        }
    }
    for (int j = 0; j < 8; j++) {
        int r = rowbase + r0 + j * 8;
        if (r >= N_NODES) continue;
        h2[(size_t)r * 64 + c0] = f2bf(acc2[j][0]);
        h2[(size_t)r * 64 + c0 + 32] = f2bf(acc2[j][1]);
    }
}

extern "C" void kernel_launch(void* const* d_in, const int* in_sizes, int n_in,
                              void* d_out, int out_size, void* d_ws, size_t ws_size,
                              hipStream_t stream) {
    const float* x  = (const float*)d_in[0];
    const float* W1 = (const float*)d_in[1];
    const float* b1 = (const float*)d_in[2];
    const float* W2 = (const float*)d_in[3];
    const float* b2 = (const float*)d_in[4];
    const int* src  = (const int*)d_in[5];
    const int* dst  = (const int*)d_in[6];
    float* out = (float*)d_out;

    int* indeg = (int*)d_ws;                        // N
    float* norm_src = (float*)(indeg + N_NODES);    // N
    float* norm_dst = norm_src + N_NODES;           // N
    int* row_start = (int*)(norm_dst + N_NODES);    // N+1
    int* tmp_incl = row_start + N_NODES + 1;        // N
    int* bsum = tmp_incl + N_NODES;                 // SCAN_BLOCKS
    int* bofs = bsum + SCAN_BLOCKS;                 // SCAN_BLOCKS
    unsigned int* rep = (unsigned int*)(bofs + SCAN_BLOCKS);      // 2*64*25000 u32
    int* edge_src = (int*)(rep + (size_t)2 * CHUNKS * REP_WORDS); // E
    int* cbase = edge_src + N_EDGES;                // 64*N ints (aliases agg1)
    float* agg1 = (float*)cbase;                    // N*64 f32 (after fill2 done)
    ushort_t* xs = (ushort_t*)(agg1 + (size_t)N_NODES * 64);  // N*64 bf16
    ushort_t* h2 = xs + (size_t)N_NODES * 64;                 // N*64 bf16

    hist_kernel<<<256, 256, 0, stream>>>(src, dst, rep);
    scan1_kernel<<<SCAN_BLOCKS, 256, 0, stream>>>(rep, indeg, tmp_incl, bsum);
    scan2_kernel<<<1, 256, 0, stream>>>(bsum, bofs, row_start);
    scan3_kernel<<<SCAN_BLOCKS, 256, 0, stream>>>(rep, indeg, tmp_incl, bofs,
                                                  row_start, norm_src, norm_dst);
    chunk_scan_kernel<<<SCAN_BLOCKS, 256, 0, stream>>>(rep, row_start, cbase);
    prescale_kernel<<<(N_NODES * 64) / 256, 256, 0, stream>>>(x, norm_src, xs);
    fill2_kernel<<<128, 256, 0, stream>>>(src, dst, cbase, edge_src);
    gather1_kernel<<<(N_NODES * 64) / 256, 256, 0, stream>>>(
        xs, edge_src, row_start, agg1);
    gemm_fused_kernel<<<(N_NODES + 63) / 64, 256, 0, stream>>>(
        agg1, W1, b1, W2, norm_dst, norm_src, h2);
    gather2_kernel<<<(N_NODES * 64) / 256, 256, 0, stream>>>(
        h2, edge_src, row_start, norm_dst, b2, out);
}

// Round 6
// 153.876 us; speedup vs baseline: 9.8319x; 1.1907x over previous
//
#include <hip/hip_runtime.h>

#define N_NODES 50000
#define N_EDGES 800000
#define SCAN_BLOCKS ((N_NODES + 255) / 256)   // 196
#define CHUNKS 64
#define EDGES_PER_CHUNK (N_EDGES / CHUNKS)    // 12500
#define HALF_NODES 25000
#define WORDS_PER_HALF 12500                  // u32 words (2 packed u16 counts each)
#define REP_WORDS 25000                       // u32 words per (arr,chunk) replica
// IN=64, HID=128, OUT=64

typedef unsigned short ushort_t;
typedef __attribute__((ext_vector_type(8))) short bf16x8;   // 8 bf16 (4 VGPRs)
typedef __attribute__((ext_vector_type(4))) float f32x4;

static __device__ __forceinline__ ushort_t f2bf(float f) {
    unsigned u = __float_as_uint(f);
    unsigned r = (u + 0x7fffu + ((u >> 16) & 1u)) >> 16;   // RNE
    return (ushort_t)r;
}
static __device__ __forceinline__ float bf2f(ushort_t u) {
    return __uint_as_float(((unsigned)u) << 16);
}

// Per-chunk privatized histogram: block (arr, half, chunk) counts its 12500
// edges' ids falling in its node-half into packed-u16 LDS counters, then
// writes the 50KB replica non-atomically. No global atomics.
__global__ __launch_bounds__(256) void hist_kernel(const int* __restrict__ src,
                                                   const int* __restrict__ dst,
                                                   unsigned int* __restrict__ rep) {
    __shared__ unsigned int cnt[WORDS_PER_HALF];
    int bid = blockIdx.x;
    int chunk = bid & 63;
    int hf = (bid >> 6) & 1;
    int arr = bid >> 7;
    const int* ids = arr ? dst : src;
    int tid = threadIdx.x;
    for (int i = tid; i < WORDS_PER_HALF; i += 256) cnt[i] = 0;
    __syncthreads();
    int base = hf * HALF_NODES;
    int ebeg = chunk * EDGES_PER_CHUNK;
    for (int i = tid; i < EDGES_PER_CHUNK; i += 256) {
        int v = ids[ebeg + i] - base;
        if ((unsigned)v < (unsigned)HALF_NODES)
            atomicAdd(&cnt[v >> 1], 1u << ((v & 1) << 4));  // LDS atomic, packed u16
    }
    __syncthreads();
    unsigned int* o = rep + ((size_t)arr * CHUNKS + chunk) * REP_WORDS + hf * WORDS_PER_HALF;
    for (int i = tid; i < WORDS_PER_HALF; i += 256) o[i] = cnt[i];
}

// Stage 1: reduce dst replicas -> indeg; per-block inclusive scan -> tmp_incl, bsum.
__global__ __launch_bounds__(256) void scan1_kernel(const unsigned int* __restrict__ rep,
                                                    int* __restrict__ indeg,
                                                    int* __restrict__ tmp_incl,
                                                    int* __restrict__ bsum) {
    __shared__ int lds[256];
    int tid = threadIdx.x;
    int i = blockIdx.x * 256 + tid;
    int v = 0;
    if (i < N_NODES) {
        int w = i >> 1, sh = (i & 1) << 4;
        const unsigned int* repd = rep + (size_t)CHUNKS * REP_WORDS;  // arr=1 (dst)
        #pragma unroll 8
        for (int c = 0; c < CHUNKS; c++)
            v += (int)((repd[(size_t)c * REP_WORDS + w] >> sh) & 0xffffu);
        indeg[i] = v;
    }
    lds[tid] = v;
    __syncthreads();
    for (int off = 1; off < 256; off <<= 1) {
        int t = (tid >= off) ? lds[tid - off] : 0;
        __syncthreads();
        lds[tid] += t;
        __syncthreads();
    }
    if (i < N_NODES) tmp_incl[i] = lds[tid];
    if (tid == 255) bsum[blockIdx.x] = lds[255];
}

// Stage 2: exclusive scan of block sums (1 block). Also writes row_start[N].
__global__ __launch_bounds__(256) void scan2_kernel(const int* __restrict__ bsum,
                                                    int* __restrict__ bofs,
                                                    int* __restrict__ row_start) {
    __shared__ int lds[256];
    int tid = threadIdx.x;
    lds[tid] = (tid < SCAN_BLOCKS) ? bsum[tid] : 0;
    __syncthreads();
    for (int off = 1; off < 256; off <<= 1) {
        int t = (tid >= off) ? lds[tid - off] : 0;
        __syncthreads();
        lds[tid] += t;
        __syncthreads();
    }
    if (tid < SCAN_BLOCKS) bofs[tid] = (tid == 0) ? 0 : lds[tid - 1];
    if (tid == SCAN_BLOCKS - 1) row_start[N_NODES] = lds[tid];
}

// Stage 3: row_start finalize + reduce src replicas -> norms.
__global__ __launch_bounds__(256) void scan3_kernel(const unsigned int* __restrict__ rep,
                                                    const int* __restrict__ indeg,
                                                    const int* __restrict__ tmp_incl,
                                                    const int* __restrict__ bofs,
                                                    int* __restrict__ row_start,
                                                    float* __restrict__ norm_src,
                                                    float* __restrict__ norm_dst) {
    int i = blockIdx.x * 256 + threadIdx.x;
    if (i >= N_NODES) return;
    int id = indeg[i];
    row_start[i] = bofs[blockIdx.x] + tmp_incl[i] - id;
    int w = i >> 1, sh = (i & 1) << 4;
    int od = 0;
    #pragma unroll 8
    for (int c = 0; c < CHUNKS; c++)
        od += (int)((rep[(size_t)c * REP_WORDS + w] >> sh) & 0xffffu);  // arr=0 (src)
    norm_src[i] = 1.0f / sqrtf((float)max(od, 1));
    norm_dst[i] = 1.0f / sqrtf((float)max(id, 1));
}

// Per-node running offset across chunks.
__global__ __launch_bounds__(256) void chunk_scan_kernel(
        const unsigned int* __restrict__ rep, const int* __restrict__ row_start,
        int* __restrict__ cbase) {
    int i = blockIdx.x * 256 + threadIdx.x;
    if (i >= N_NODES) return;
    int w = i >> 1, sh = (i & 1) << 4;
    const unsigned int* repd = rep + (size_t)CHUNKS * REP_WORDS;  // arr=1 (dst)
    int running = row_start[i];
    for (int c = 0; c < CHUNKS; c++) {
        cbase[(size_t)c * N_NODES + i] = running;
        running += (int)((repd[(size_t)c * REP_WORDS + w] >> sh) & 0xffffu);
    }
}

// Counting-sort CSR fill: block (half, chunk) ranks its edges with packed-u16
// LDS cursors; pos = cbase[chunk][dst] + rank. No global atomics.
__global__ __launch_bounds__(256) void fill2_kernel(const int* __restrict__ src,
                                                    const int* __restrict__ dst,
                                                    const int* __restrict__ cbase,
                                                    int* __restrict__ edge_src) {
    __shared__ unsigned int rank[WORDS_PER_HALF];
    int chunk = blockIdx.x & 63;
    int hf = blockIdx.x >> 6;
    int tid = threadIdx.x;
    for (int i = tid; i < WORDS_PER_HALF; i += 256) rank[i] = 0;
    __syncthreads();
    int base = hf * HALF_NODES;
    int ebeg = chunk * EDGES_PER_CHUNK;
    for (int i = tid; i < EDGES_PER_CHUNK; i += 256) {
        int d = dst[ebeg + i];
        int v = d - base;
        if ((unsigned)v < (unsigned)HALF_NODES) {
            int sh = (v & 1) << 4;
            unsigned old = atomicAdd(&rank[v >> 1], 1u << sh);
            int r = (int)((old >> sh) & 0xffffu);
            edge_src[cbase[(size_t)chunk * N_NODES + d] + r] = src[ebeg + i];
        }
    }
}

// xs = bf16(x * norm_src), row-broadcast scale.
__global__ __launch_bounds__(256) void prescale_kernel(const float* __restrict__ x,
                                                       const float* __restrict__ norm_src,
                                                       ushort_t* __restrict__ xs) {
    int t = blockIdx.x * 256 + threadIdx.x;   // over N*64, exact grid
    int row = t >> 6;
    float ns = norm_src[row];
    xs[t] = f2bf(x[t] * ns);
}

// One wave per dst node, lane = feature column. 8-deep load unroll.
__global__ __launch_bounds__(256) void gather1_kernel(
        const ushort_t* __restrict__ xs, const int* __restrict__ edge_src,
        const int* __restrict__ row_start, float* __restrict__ agg) {
    int node = (blockIdx.x * blockDim.x + threadIdx.x) >> 6;
    int lane = threadIdx.x & 63;
    int beg = row_start[node];
    int end = row_start[node + 1];
    float a0 = 0.f, a1 = 0.f, a2 = 0.f, a3 = 0.f;
    for (int i = beg; i < end; i += 64) {
        int cnt = min(end - i, 64);
        int ids = (lane < cnt) ? edge_src[i + lane] : 0;
        int j = 0;
        for (; j + 8 <= cnt; j += 8) {
            int s0 = __builtin_amdgcn_readlane(ids, j);
            int s1 = __builtin_amdgcn_readlane(ids, j + 1);
            int s2 = __builtin_amdgcn_readlane(ids, j + 2);
            int s3 = __builtin_amdgcn_readlane(ids, j + 3);
            int s4 = __builtin_amdgcn_readlane(ids, j + 4);
            int s5 = __builtin_amdgcn_readlane(ids, j + 5);
            int s6 = __builtin_amdgcn_readlane(ids, j + 6);
            int s7 = __builtin_amdgcn_readlane(ids, j + 7);
            float v0 = bf2f(xs[(size_t)s0 * 64 + lane]);
            float v1 = bf2f(xs[(size_t)s1 * 64 + lane]);
            float v2 = bf2f(xs[(size_t)s2 * 64 + lane]);
            float v3 = bf2f(xs[(size_t)s3 * 64 + lane]);
            float v4 = bf2f(xs[(size_t)s4 * 64 + lane]);
            float v5 = bf2f(xs[(size_t)s5 * 64 + lane]);
            float v6 = bf2f(xs[(size_t)s6 * 64 + lane]);
            float v7 = bf2f(xs[(size_t)s7 * 64 + lane]);
            a0 += v0; a1 += v1; a2 += v2; a3 += v3;
            a0 += v4; a1 += v5; a2 += v6; a3 += v7;
        }
        for (; j < cnt; j++) {
            int s = __builtin_amdgcn_readlane(ids, j);
            a0 += bf2f(xs[(size_t)s * 64 + lane]);
        }
    }
    agg[(size_t)node * 64 + lane] = (a0 + a1) + (a2 + a3);
}

__global__ __launch_bounds__(256) void gather2_kernel(
        const ushort_t* __restrict__ h2, const int* __restrict__ edge_src,
        const int* __restrict__ row_start, const float* __restrict__ norm_dst,
        const float* __restrict__ b2, float* __restrict__ out) {
    int node = (blockIdx.x * blockDim.x + threadIdx.x) >> 6;
    int lane = threadIdx.x & 63;
    int beg = row_start[node];
    int end = row_start[node + 1];
    float a0 = 0.f, a1 = 0.f, a2 = 0.f, a3 = 0.f;
    for (int i = beg; i < end; i += 64) {
        int cnt = min(end - i, 64);
        int ids = (lane < cnt) ? edge_src[i + lane] : 0;
        int j = 0;
        for (; j + 8 <= cnt; j += 8) {
            int s0 = __builtin_amdgcn_readlane(ids, j);
            int s1 = __builtin_amdgcn_readlane(ids, j + 1);
            int s2 = __builtin_amdgcn_readlane(ids, j + 2);
            int s3 = __builtin_amdgcn_readlane(ids, j + 3);
            int s4 = __builtin_amdgcn_readlane(ids, j + 4);
            int s5 = __builtin_amdgcn_readlane(ids, j + 5);
            int s6 = __builtin_amdgcn_readlane(ids, j + 6);
            int s7 = __builtin_amdgcn_readlane(ids, j + 7);
            float v0 = bf2f(h2[(size_t)s0 * 64 + lane]);
            float v1 = bf2f(h2[(size_t)s1 * 64 + lane]);
            float v2 = bf2f(h2[(size_t)s2 * 64 + lane]);
            float v3 = bf2f(h2[(size_t)s3 * 64 + lane]);
            float v4 = bf2f(h2[(size_t)s4 * 64 + lane]);
            float v5 = bf2f(h2[(size_t)s5 * 64 + lane]);
            float v6 = bf2f(h2[(size_t)s6 * 64 + lane]);
            float v7 = bf2f(h2[(size_t)s7 * 64 + lane]);
            a0 += v0; a1 += v1; a2 += v2; a3 += v3;
            a0 += v4; a1 += v5; a2 += v6; a3 += v7;
        }
        for (; j < cnt; j++) {
            int s = __builtin_amdgcn_readlane(ids, j);
            a0 += bf2f(h2[(size_t)s * 64 + lane]);
        }
    }
    float acc = (a0 + a1) + (a2 + a3);
    out[(size_t)node * 64 + lane] = acc * norm_dst[node] + b2[lane];
}

// MFMA fused MLP. Per block: 64 rows, 4 waves, each wave owns 16 rows.
// Layer1: [64x64]@[64x128] via hi/lo-split bf16 A (fp32-grade A). Layer2:
// [64x128]@[128x64] single bf16. Row padding (72/136 u16) spreads LDS banks.
__global__ __launch_bounds__(256) void gemm_fused_kernel(
        const float* __restrict__ agg, const float* __restrict__ W1,
        const float* __restrict__ b1, const float* __restrict__ W2,
        const float* __restrict__ norm_dst, const float* __restrict__ norm_src,
        ushort_t* __restrict__ h2) {
    __shared__ ushort_t mem[18432];   // 36 KB
    ushort_t* As_hi = mem;            // [64][72]
    ushort_t* As_lo = mem + 4608;     // [64][72]
    ushort_t* Wt1   = mem + 9216;     // [128 n][72 k]
    int tid = threadIdx.x;
    int rowbase = blockIdx.x * 64;

    // Stage W1 transposed -> bf16.
    for (int i = tid; i < 8192; i += 256) {
        int k = i >> 7, n = i & 127;
        Wt1[n * 72 + k] = f2bf(W1[i]);
    }
    // Stage agg rows as hi/lo bf16 pair.
    for (int i = tid; i < 1024; i += 256) {
        int row = i >> 4;
        int c = (i & 15) * 4;
        int gr = rowbase + row;
        float4 v = make_float4(0.f, 0.f, 0.f, 0.f);
        if (gr < N_NODES) v = *(const float4*)&agg[(size_t)gr * 64 + c];
        float va[4] = {v.x, v.y, v.z, v.w};
        int base = row * 72 + c;
        #pragma unroll
        for (int q = 0; q < 4; q++) {
            ushort_t h = f2bf(va[q]);
            As_hi[base + q] = h;
            As_lo[base + q] = f2bf(va[q] - bf2f(h));
        }
    }
    __syncthreads();

    int lane = tid & 63;
    int w = tid >> 6;          // wave id 0..3 -> rows 16w..16w+15
    int lr = lane & 15;        // A-row / B-col within tile
    int hi8 = lane >> 4;       // k-group 0..3
    int a_off = (16 * w + lr) * 72 + hi8 * 8;

    f32x4 acc[8] = {};
    #pragma unroll
    for (int ks = 0; ks < 2; ks++) {
        bf16x8 ah = *(bf16x8*)&As_hi[a_off + ks * 32];
        bf16x8 al = *(bf16x8*)&As_lo[a_off + ks * 32];
        #pragma unroll
        for (int ct = 0; ct < 8; ct++) {
            bf16x8 b = *(bf16x8*)&Wt1[(ct * 16 + lr) * 72 + ks * 32 + hi8 * 8];
            acc[ct] = __builtin_amdgcn_mfma_f32_16x16x32_bf16(ah, b, acc[ct], 0, 0, 0);
            acc[ct] = __builtin_amdgcn_mfma_f32_16x16x32_bf16(al, b, acc[ct], 0, 0, 0);
        }
    }

    // Norms for this lane's 4 output rows (C/D: row=(lane>>4)*4+reg, col=lane&15).
    int row4 = hi8 * 4;
    float nd[4], ns[4];
    #pragma unroll
    for (int r = 0; r < 4; r++) {
        int gr = rowbase + 16 * w + row4 + r;
        nd[r] = (gr < N_NODES) ? norm_dst[gr] : 0.f;
        ns[r] = (gr < N_NODES) ? norm_src[gr] : 0.f;
    }
    __syncthreads();   // all waves done reading As/Wt1

    ushort_t* Hs  = mem;          // [64][136]
    ushort_t* Wt2 = mem + 8704;   // [64 n][136 k]
    for (int i = tid; i < 8192; i += 256) {
        int k = i >> 6, n = i & 63;
        Wt2[n * 136 + k] = f2bf(W2[i]);
    }
    #pragma unroll
    for (int ct = 0; ct < 8; ct++) {
        float bb = b1[ct * 16 + lr];
        #pragma unroll
        for (int r = 0; r < 4; r++) {
            float v = fmaxf(acc[ct][r] * nd[r] + bb, 0.f) * ns[r];
            Hs[(16 * w + row4 + r) * 136 + ct * 16 + lr] = f2bf(v);
        }
    }
    __syncthreads();

    f32x4 acc2[4] = {};
    int a2_off = (16 * w + lr) * 136 + hi8 * 8;
    #pragma unroll
    for (int ks = 0; ks < 4; ks++) {
        bf16x8 a2 = *(bf16x8*)&Hs[a2_off + ks * 32];
        #pragma unroll
        for (int ct = 0; ct < 4; ct++) {
            bf16x8 b = *(bf16x8*)&Wt2[(ct * 16 + lr) * 136 + ks * 32 + hi8 * 8];
            acc2[ct] = __builtin_amdgcn_mfma_f32_16x16x32_bf16(a2, b, acc2[ct], 0, 0, 0);
        }
    }
    #pragma unroll
    for (int ct = 0; ct < 4; ct++) {
        #pragma unroll
        for (int r = 0; r < 4; r++) {
            int gr = rowbase + 16 * w + row4 + r;
            if (gr < N_NODES)
                h2[(size_t)gr * 64 + ct * 16 + lr] = f2bf(acc2[ct][r]);
        }
    }
}

extern "C" void kernel_launch(void* const* d_in, const int* in_sizes, int n_in,
                              void* d_out, int out_size, void* d_ws, size_t ws_size,
                              hipStream_t stream) {
    const float* x  = (const float*)d_in[0];
    const float* W1 = (const float*)d_in[1];
    const float* b1 = (const float*)d_in[2];
    const float* W2 = (const float*)d_in[3];
    const float* b2 = (const float*)d_in[4];
    const int* src  = (const int*)d_in[5];
    const int* dst  = (const int*)d_in[6];
    float* out = (float*)d_out;

    int* indeg = (int*)d_ws;                        // N
    float* norm_src = (float*)(indeg + N_NODES);    // N
    float* norm_dst = norm_src + N_NODES;           // N
    int* row_start = (int*)(norm_dst + N_NODES);    // N+1
    int* tmp_incl = row_start + N_NODES + 1;        // N
    int* bsum = tmp_incl + N_NODES;                 // SCAN_BLOCKS
    int* bofs = bsum + SCAN_BLOCKS;                 // SCAN_BLOCKS
    unsigned int* rep = (unsigned int*)(bofs + SCAN_BLOCKS);      // 2*64*25000 u32
    int* edge_src = (int*)(rep + (size_t)2 * CHUNKS * REP_WORDS); // E
    int* cbase = edge_src + N_EDGES;                // 64*N ints (aliases agg1)
    float* agg1 = (float*)cbase;                    // N*64 f32 (after fill2 done)
    ushort_t* xs = (ushort_t*)(agg1 + (size_t)N_NODES * 64);  // N*64 bf16
    ushort_t* h2 = xs + (size_t)N_NODES * 64;                 // N*64 bf16

    hist_kernel<<<256, 256, 0, stream>>>(src, dst, rep);
    scan1_kernel<<<SCAN_BLOCKS, 256, 0, stream>>>(rep, indeg, tmp_incl, bsum);
    scan2_kernel<<<1, 256, 0, stream>>>(bsum, bofs, row_start);
    scan3_kernel<<<SCAN_BLOCKS, 256, 0, stream>>>(rep, indeg, tmp_incl, bofs,
                                                  row_start, norm_src, norm_dst);
    chunk_scan_kernel<<<SCAN_BLOCKS, 256, 0, stream>>>(rep, row_start, cbase);
    prescale_kernel<<<(N_NODES * 64) / 256, 256, 0, stream>>>(x, norm_src, xs);
    fill2_kernel<<<128, 256, 0, stream>>>(src, dst, cbase, edge_src);
    gather1_kernel<<<(N_NODES * 64) / 256, 256, 0, stream>>>(
        xs, edge_src, row_start, agg1);
    gemm_fused_kernel<<<(N_NODES + 63) / 64, 256, 0, stream>>>(
        agg1, W1, b1, W2, norm_dst, norm_src, h2);
    gather2_kernel<<<(N_NODES * 64) / 256, 256, 0, stream>>>(
        h2, edge_src, row_start, norm_dst, b2, out);
}

// Round 7
// 137.749 us; speedup vs baseline: 10.9830x; 1.1171x over previous
//
#include <hip/hip_runtime.h>

#define N_NODES 50000
#define N_EDGES 800000
#define SCAN_BLOCKS ((N_NODES + 255) / 256)   // 196
#define CHUNKS 64
#define EDGES_PER_CHUNK (N_EDGES / CHUNKS)    // 12500
#define HALF_NODES 25000
#define WORDS_PER_HALF 12500                  // u32 words (2 packed u16 counts each)
#define REP_WORDS 25000                       // u32 words per (arr,chunk) replica
// IN=64, HID=128, OUT=64

typedef unsigned short ushort_t;
typedef __attribute__((ext_vector_type(8))) short bf16x8;   // 8 bf16 (4 VGPRs)
typedef __attribute__((ext_vector_type(4))) float f32x4;

static __device__ __forceinline__ ushort_t f2bf(float f) {
    unsigned u = __float_as_uint(f);
    unsigned r = (u + 0x7fffu + ((u >> 16) & 1u)) >> 16;   // RNE
    return (ushort_t)r;
}
static __device__ __forceinline__ float bf2f(ushort_t u) {
    return __uint_as_float(((unsigned)u) << 16);
}

// Per-chunk privatized histogram: block (arr, half, chunk) counts its 12500
// edges' ids falling in its node-half into packed-u16 LDS counters, then
// writes the 50KB replica non-atomically. No global atomics.
__global__ __launch_bounds__(256) void hist_kernel(const int* __restrict__ src,
                                                   const int* __restrict__ dst,
                                                   unsigned int* __restrict__ rep) {
    __shared__ unsigned int cnt[WORDS_PER_HALF];
    int bid = blockIdx.x;
    int chunk = bid & 63;
    int hf = (bid >> 6) & 1;
    int arr = bid >> 7;
    const int* ids = arr ? dst : src;
    int tid = threadIdx.x;
    for (int i = tid; i < WORDS_PER_HALF; i += 256) cnt[i] = 0;
    __syncthreads();
    int base = hf * HALF_NODES;
    int ebeg = chunk * EDGES_PER_CHUNK;
    for (int i = tid; i < EDGES_PER_CHUNK; i += 256) {
        int v = ids[ebeg + i] - base;
        if ((unsigned)v < (unsigned)HALF_NODES)
            atomicAdd(&cnt[v >> 1], 1u << ((v & 1) << 4));  // LDS atomic, packed u16
    }
    __syncthreads();
    unsigned int* o = rep + ((size_t)arr * CHUNKS + chunk) * REP_WORDS + hf * WORDS_PER_HALF;
    for (int i = tid; i < WORDS_PER_HALF; i += 256) o[i] = cnt[i];
}

// Stage 1: reduce dst replicas -> indeg; per-block inclusive scan -> tmp_incl, bsum.
__global__ __launch_bounds__(256) void scan1_kernel(const unsigned int* __restrict__ rep,
                                                    int* __restrict__ indeg,
                                                    int* __restrict__ tmp_incl,
                                                    int* __restrict__ bsum) {
    __shared__ int lds[256];
    int tid = threadIdx.x;
    int i = blockIdx.x * 256 + tid;
    int v = 0;
    if (i < N_NODES) {
        int w = i >> 1, sh = (i & 1) << 4;
        const unsigned int* repd = rep + (size_t)CHUNKS * REP_WORDS;  // arr=1 (dst)
        #pragma unroll 8
        for (int c = 0; c < CHUNKS; c++)
            v += (int)((repd[(size_t)c * REP_WORDS + w] >> sh) & 0xffffu);
        indeg[i] = v;
    }
    lds[tid] = v;
    __syncthreads();
    for (int off = 1; off < 256; off <<= 1) {
        int t = (tid >= off) ? lds[tid - off] : 0;
        __syncthreads();
        lds[tid] += t;
        __syncthreads();
    }
    if (i < N_NODES) tmp_incl[i] = lds[tid];
    if (tid == 255) bsum[blockIdx.x] = lds[255];
}

// Stage 2: exclusive scan of block sums (1 block). Also writes row_start[N].
__global__ __launch_bounds__(256) void scan2_kernel(const int* __restrict__ bsum,
                                                    int* __restrict__ bofs,
                                                    int* __restrict__ row_start) {
    __shared__ int lds[256];
    int tid = threadIdx.x;
    lds[tid] = (tid < SCAN_BLOCKS) ? bsum[tid] : 0;
    __syncthreads();
    for (int off = 1; off < 256; off <<= 1) {
        int t = (tid >= off) ? lds[tid - off] : 0;
        __syncthreads();
        lds[tid] += t;
        __syncthreads();
    }
    if (tid < SCAN_BLOCKS) bofs[tid] = (tid == 0) ? 0 : lds[tid - 1];
    if (tid == SCAN_BLOCKS - 1) row_start[N_NODES] = lds[tid];
}

// Stage 3: row_start finalize + norms + per-chunk cbase running offsets (fused).
__global__ __launch_bounds__(256) void scan3_kernel(const unsigned int* __restrict__ rep,
                                                    const int* __restrict__ indeg,
                                                    const int* __restrict__ tmp_incl,
                                                    const int* __restrict__ bofs,
                                                    int* __restrict__ row_start,
                                                    float* __restrict__ norm_src,
                                                    float* __restrict__ norm_dst,
                                                    int* __restrict__ cbase) {
    int i = blockIdx.x * 256 + threadIdx.x;
    if (i >= N_NODES) return;
    int id = indeg[i];
    int rs = bofs[blockIdx.x] + tmp_incl[i] - id;
    row_start[i] = rs;
    int w = i >> 1, sh = (i & 1) << 4;
    int od = 0;
    #pragma unroll 8
    for (int c = 0; c < CHUNKS; c++)
        od += (int)((rep[(size_t)c * REP_WORDS + w] >> sh) & 0xffffu);  // arr=0 (src)
    norm_src[i] = 1.0f / sqrtf((float)max(od, 1));
    norm_dst[i] = 1.0f / sqrtf((float)max(id, 1));
    const unsigned int* repd = rep + (size_t)CHUNKS * REP_WORDS;  // arr=1 (dst)
    int running = rs;
    for (int c = 0; c < CHUNKS; c++) {
        cbase[(size_t)c * N_NODES + i] = running;
        running += (int)((repd[(size_t)c * REP_WORDS + w] >> sh) & 0xffffu);
    }
}

// Counting-sort CSR fill: block (half, chunk) ranks its edges with packed-u16
// LDS cursors; pos = cbase[chunk][dst] + rank. No global atomics.
__global__ __launch_bounds__(256) void fill2_kernel(const int* __restrict__ src,
                                                    const int* __restrict__ dst,
                                                    const int* __restrict__ cbase,
                                                    int* __restrict__ edge_src) {
    __shared__ unsigned int rank[WORDS_PER_HALF];
    int chunk = blockIdx.x & 63;
    int hf = blockIdx.x >> 6;
    int tid = threadIdx.x;
    for (int i = tid; i < WORDS_PER_HALF; i += 256) rank[i] = 0;
    __syncthreads();
    int base = hf * HALF_NODES;
    int ebeg = chunk * EDGES_PER_CHUNK;
    for (int i = tid; i < EDGES_PER_CHUNK; i += 256) {
        int d = dst[ebeg + i];
        int v = d - base;
        if ((unsigned)v < (unsigned)HALF_NODES) {
            int sh = (v & 1) << 4;
            unsigned old = atomicAdd(&rank[v >> 1], 1u << sh);
            int r = (int)((old >> sh) & 0xffffu);
            edge_src[cbase[(size_t)chunk * N_NODES + d] + r] = src[ebeg + i];
        }
    }
}

// xs = bf16(x * norm_src), row-broadcast scale.
__global__ __launch_bounds__(256) void prescale_kernel(const float* __restrict__ x,
                                                       const float* __restrict__ norm_src,
                                                       ushort_t* __restrict__ xs) {
    int t = blockIdx.x * 256 + threadIdx.x;   // over N*64, exact grid
    int row = t >> 6;
    float ns = norm_src[row];
    xs[t] = f2bf(x[t] * ns);
}

// Quad-row gather: one wave per node; 4 lane-groups of 16 handle 4 edges per
// step, each group's 16 lanes load dwordx2 (4 bf16 cols) of its row -> 4 rows
// per load instruction, 16 rows in flight at unroll 4. bpermute broadcasts ids.
__global__ __launch_bounds__(256) void gather1_kernel(
        const ushort_t* __restrict__ xs, const int* __restrict__ edge_src,
        const int* __restrict__ row_start, float* __restrict__ agg) {
    int node = (blockIdx.x * blockDim.x + threadIdx.x) >> 6;
    int lane = threadIdx.x & 63;
    int grp = lane >> 4;        // edge sub-stream 0..3
    int lpos = lane & 15;       // column quad: cols 4*lpos..4*lpos+3
    int beg = row_start[node];
    int end = row_start[node + 1];
    float a0 = 0.f, a1 = 0.f, a2 = 0.f, a3 = 0.f;
    for (int i = beg; i < end; i += 64) {
        int cnt = min(end - i, 64);
        int ids = (lane < cnt) ? edge_src[i + lane] : 0;
        for (int t = 0; t < cnt; t += 16) {
            #pragma unroll
            for (int q = 0; q < 4; q++) {
                int j = t + 4 * q + grp;
                int jj = max(min(j, cnt - 1), 0);
                int s = __builtin_amdgcn_ds_bpermute(jj << 2, ids);
                uint2 v = *(const uint2*)&xs[(size_t)s * 64 + lpos * 4];
                float m = (j < cnt) ? 1.f : 0.f;
                a0 = fmaf(__uint_as_float(v.x << 16), m, a0);
                a1 = fmaf(__uint_as_float(v.x & 0xffff0000u), m, a1);
                a2 = fmaf(__uint_as_float(v.y << 16), m, a2);
                a3 = fmaf(__uint_as_float(v.y & 0xffff0000u), m, a3);
            }
        }
    }
    a0 += __shfl_xor(a0, 16, 64); a1 += __shfl_xor(a1, 16, 64);
    a2 += __shfl_xor(a2, 16, 64); a3 += __shfl_xor(a3, 16, 64);
    a0 += __shfl_xor(a0, 32, 64); a1 += __shfl_xor(a1, 32, 64);
    a2 += __shfl_xor(a2, 32, 64); a3 += __shfl_xor(a3, 32, 64);
    if (grp == 0)
        *(float4*)&agg[(size_t)node * 64 + lpos * 4] = make_float4(a0, a1, a2, a3);
}

__global__ __launch_bounds__(256) void gather2_kernel(
        const ushort_t* __restrict__ h2, const int* __restrict__ edge_src,
        const int* __restrict__ row_start, const float* __restrict__ norm_dst,
        const float* __restrict__ b2, float* __restrict__ out) {
    int node = (blockIdx.x * blockDim.x + threadIdx.x) >> 6;
    int lane = threadIdx.x & 63;
    int grp = lane >> 4;
    int lpos = lane & 15;
    int beg = row_start[node];
    int end = row_start[node + 1];
    float a0 = 0.f, a1 = 0.f, a2 = 0.f, a3 = 0.f;
    for (int i = beg; i < end; i += 64) {
        int cnt = min(end - i, 64);
        int ids = (lane < cnt) ? edge_src[i + lane] : 0;
        for (int t = 0; t < cnt; t += 16) {
            #pragma unroll
            for (int q = 0; q < 4; q++) {
                int j = t + 4 * q + grp;
                int jj = max(min(j, cnt - 1), 0);
                int s = __builtin_amdgcn_ds_bpermute(jj << 2, ids);
                uint2 v = *(const uint2*)&h2[(size_t)s * 64 + lpos * 4];
                float m = (j < cnt) ? 1.f : 0.f;
                a0 = fmaf(__uint_as_float(v.x << 16), m, a0);
                a1 = fmaf(__uint_as_float(v.x & 0xffff0000u), m, a1);
                a2 = fmaf(__uint_as_float(v.y << 16), m, a2);
                a3 = fmaf(__uint_as_float(v.y & 0xffff0000u), m, a3);
            }
        }
    }
    a0 += __shfl_xor(a0, 16, 64); a1 += __shfl_xor(a1, 16, 64);
    a2 += __shfl_xor(a2, 16, 64); a3 += __shfl_xor(a3, 16, 64);
    a0 += __shfl_xor(a0, 32, 64); a1 += __shfl_xor(a1, 32, 64);
    a2 += __shfl_xor(a2, 32, 64); a3 += __shfl_xor(a3, 32, 64);
    if (grp == 0) {
        float nd = norm_dst[node];
        float4 bb = *(const float4*)&b2[lpos * 4];
        *(float4*)&out[(size_t)node * 64 + lpos * 4] =
            make_float4(a0 * nd + bb.x, a1 * nd + bb.y, a2 * nd + bb.z, a3 * nd + bb.w);
    }
}

// MFMA fused MLP. Per block: 64 rows, 4 waves, each wave owns 16 rows.
// Layer1: [64x64]@[64x128] via hi/lo-split bf16 A (fp32-grade A). Layer2:
// [64x128]@[128x64] single bf16. Row padding (72/136 u16) spreads LDS banks.
__global__ __launch_bounds__(256) void gemm_fused_kernel(
        const float* __restrict__ agg, const float* __restrict__ W1,
        const float* __restrict__ b1, const float* __restrict__ W2,
        const float* __restrict__ norm_dst, const float* __restrict__ norm_src,
        ushort_t* __restrict__ h2) {
    __shared__ ushort_t mem[18432];   // 36 KB
    ushort_t* As_hi = mem;            // [64][72]
    ushort_t* As_lo = mem + 4608;     // [64][72]
    ushort_t* Wt1   = mem + 9216;     // [128 n][72 k]
    int tid = threadIdx.x;
    int rowbase = blockIdx.x * 64;

    // Stage W1 transposed -> bf16.
    for (int i = tid; i < 8192; i += 256) {
        int k = i >> 7, n = i & 127;
        Wt1[n * 72 + k] = f2bf(W1[i]);
    }
    // Stage agg rows as hi/lo bf16 pair.
    for (int i = tid; i < 1024; i += 256) {
        int row = i >> 4;
        int c = (i & 15) * 4;
        int gr = rowbase + row;
        float4 v = make_float4(0.f, 0.f, 0.f, 0.f);
        if (gr < N_NODES) v = *(const float4*)&agg[(size_t)gr * 64 + c];
        float va[4] = {v.x, v.y, v.z, v.w};
        int base = row * 72 + c;
        #pragma unroll
        for (int q = 0; q < 4; q++) {
            ushort_t h = f2bf(va[q]);
            As_hi[base + q] = h;
            As_lo[base + q] = f2bf(va[q] - bf2f(h));
        }
    }
    __syncthreads();

    int lane = tid & 63;
    int w = tid >> 6;          // wave id 0..3 -> rows 16w..16w+15
    int lr = lane & 15;        // A-row / B-col within tile
    int hi8 = lane >> 4;       // k-group 0..3
    int a_off = (16 * w + lr) * 72 + hi8 * 8;

    f32x4 acc[8] = {};
    #pragma unroll
    for (int ks = 0; ks < 2; ks++) {
        bf16x8 ah = *(bf16x8*)&As_hi[a_off + ks * 32];
        bf16x8 al = *(bf16x8*)&As_lo[a_off + ks * 32];
        #pragma unroll
        for (int ct = 0; ct < 8; ct++) {
            bf16x8 b = *(bf16x8*)&Wt1[(ct * 16 + lr) * 72 + ks * 32 + hi8 * 8];
            acc[ct] = __builtin_amdgcn_mfma_f32_16x16x32_bf16(ah, b, acc[ct], 0, 0, 0);
            acc[ct] = __builtin_amdgcn_mfma_f32_16x16x32_bf16(al, b, acc[ct], 0, 0, 0);
        }
    }

    // Norms for this lane's 4 output rows (C/D: row=(lane>>4)*4+reg, col=lane&15).
    int row4 = hi8 * 4;
    float nd[4], ns[4];
    #pragma unroll
    for (int r = 0; r < 4; r++) {
        int gr = rowbase + 16 * w + row4 + r;
        nd[r] = (gr < N_NODES) ? norm_dst[gr] : 0.f;
        ns[r] = (gr < N_NODES) ? norm_src[gr] : 0.f;
    }
    __syncthreads();   // all waves done reading As/Wt1

    ushort_t* Hs  = mem;          // [64][136]
    ushort_t* Wt2 = mem + 8704;   // [64 n][136 k]
    for (int i = tid; i < 8192; i += 256) {
        int k = i >> 6, n = i & 63;
        Wt2[n * 136 + k] = f2bf(W2[i]);
    }
    #pragma unroll
    for (int ct = 0; ct < 8; ct++) {
        float bb = b1[ct * 16 + lr];
        #pragma unroll
        for (int r = 0; r < 4; r++) {
            float v = fmaxf(acc[ct][r] * nd[r] + bb, 0.f) * ns[r];
            Hs[(16 * w + row4 + r) * 136 + ct * 16 + lr] = f2bf(v);
        }
    }
    __syncthreads();

    f32x4 acc2[4] = {};
    int a2_off = (16 * w + lr) * 136 + hi8 * 8;
    #pragma unroll
    for (int ks = 0; ks < 4; ks++) {
        bf16x8 a2 = *(bf16x8*)&Hs[a2_off + ks * 32];
        #pragma unroll
        for (int ct = 0; ct < 4; ct++) {
            bf16x8 b = *(bf16x8*)&Wt2[(ct * 16 + lr) * 136 + ks * 32 + hi8 * 8];
            acc2[ct] = __builtin_amdgcn_mfma_f32_16x16x32_bf16(a2, b, acc2[ct], 0, 0, 0);
        }
    }
    #pragma unroll
    for (int ct = 0; ct < 4; ct++) {
        #pragma unroll
        for (int r = 0; r < 4; r++) {
            int gr = rowbase + 16 * w + row4 + r;
            if (gr < N_NODES)
                h2[(size_t)gr * 64 + ct * 16 + lr] = f2bf(acc2[ct][r]);
        }
    }
}

extern "C" void kernel_launch(void* const* d_in, const int* in_sizes, int n_in,
                              void* d_out, int out_size, void* d_ws, size_t ws_size,
                              hipStream_t stream) {
    const float* x  = (const float*)d_in[0];
    const float* W1 = (const float*)d_in[1];
    const float* b1 = (const float*)d_in[2];
    const float* W2 = (const float*)d_in[3];
    const float* b2 = (const float*)d_in[4];
    const int* src  = (const int*)d_in[5];
    const int* dst  = (const int*)d_in[6];
    float* out = (float*)d_out;

    int* indeg = (int*)d_ws;                        // N
    float* norm_src = (float*)(indeg + N_NODES);    // N
    float* norm_dst = norm_src + N_NODES;           // N
    int* row_start = (int*)(norm_dst + N_NODES);    // N+1
    int* tmp_incl = row_start + N_NODES + 1;        // N
    int* bsum = tmp_incl + N_NODES;                 // SCAN_BLOCKS
    int* bofs = bsum + SCAN_BLOCKS;                 // SCAN_BLOCKS
    unsigned int* rep = (unsigned int*)(bofs + SCAN_BLOCKS);      // 2*64*25000 u32
    int* edge_src = (int*)(rep + (size_t)2 * CHUNKS * REP_WORDS); // E
    int* cbase = edge_src + N_EDGES;                // 64*N ints (aliases agg1)
    float* agg1 = (float*)cbase;                    // N*64 f32 (after fill2 done)
    ushort_t* xs = (ushort_t*)(agg1 + (size_t)N_NODES * 64);  // N*64 bf16
    ushort_t* h2 = xs + (size_t)N_NODES * 64;                 // N*64 bf16

    hist_kernel<<<256, 256, 0, stream>>>(src, dst, rep);
    scan1_kernel<<<SCAN_BLOCKS, 256, 0, stream>>>(rep, indeg, tmp_incl, bsum);
    scan2_kernel<<<1, 256, 0, stream>>>(bsum, bofs, row_start);
    scan3_kernel<<<SCAN_BLOCKS, 256, 0, stream>>>(rep, indeg, tmp_incl, bofs,
                                                  row_start, norm_src, norm_dst, cbase);
    prescale_kernel<<<(N_NODES * 64) / 256, 256, 0, stream>>>(x, norm_src, xs);
    fill2_kernel<<<128, 256, 0, stream>>>(src, dst, cbase, edge_src);
    gather1_kernel<<<(N_NODES * 64) / 256, 256, 0, stream>>>(
        xs, edge_src, row_start, agg1);
    gemm_fused_kernel<<<(N_NODES + 63) / 64, 256, 0, stream>>>(
        agg1, W1, b1, W2, norm_dst, norm_src, h2);
    gather2_kernel<<<(N_NODES * 64) / 256, 256, 0, stream>>>(
        h2, edge_src, row_start, norm_dst, b2, out);
}